// Round 7
// baseline (346.648 us; speedup 1.0000x reference)
//
#include <hip/hip_runtime.h>
#include <math.h>

#define NN 32768
#define NE 262144
#define NG 256
#define DIN 256
#define DH 512
#define DOUT 512

typedef unsigned short u16;
typedef _Float16 f16;
typedef __attribute__((ext_vector_type(4))) _Float16 f16x4;
typedef __attribute__((ext_vector_type(8))) _Float16 f16x8;
typedef __attribute__((ext_vector_type(8))) short short8;
typedef __attribute__((ext_vector_type(4))) float f32x4;

__device__ inline u16 bf16rn(float f) {
  unsigned u = __float_as_uint(f);
  return (u16)((u + 0x7fff + ((u >> 16) & 1)) >> 16);
}
__device__ inline float bfbits(u16 b) { return __uint_as_float(((unsigned)b) << 16); }
__device__ inline void split2(float f, u16& h, u16& l) {
  h = bf16rn(f);
  float r = f - bfbits(h);
  l = bf16rn(r);
}

__device__ inline void gload16(const void* g, void* l) {
  __builtin_amdgcn_global_load_lds((const __attribute__((address_space(1))) unsigned int*)g,
                                   (__attribute__((address_space(3))) unsigned int*)l,
                                   16, 0, 0);
}

// ---------------- graph prep ----------------

__global__ void k_count(const int* __restrict__ ei, int* __restrict__ counts) {
  int e = blockIdx.x * 256 + threadIdx.x;
  if (e < NE) atomicAdd(&counts[ei[NE + e]], 1);
}

// hierarchical scan: A) per-block reduce, B) scan of block sums, C) apply + local scan + dinv
__global__ __launch_bounds__(128) void k_scanA(const int* __restrict__ counts,
                                               int* __restrict__ bsum) {
  int b = blockIdx.x, t = threadIdx.x;
  int v = counts[b * 128 + t];
  __shared__ int red[128];
  red[t] = v;
  __syncthreads();
#pragma unroll
  for (int o = 64; o > 0; o >>= 1) {
    if (t < o) red[t] += red[t + o];
    __syncthreads();
  }
  if (t == 0) bsum[b] = red[0];
}

__global__ __launch_bounds__(256) void k_scanB(const int* __restrict__ bsum,
                                               int* __restrict__ boff,
                                               int* __restrict__ offs) {
  __shared__ int s[256];
  int t = threadIdx.x;
  int v = bsum[t];
  s[t] = v;
  __syncthreads();
  for (int o = 1; o < 256; o <<= 1) {
    int add = (t >= o) ? s[t - o] : 0;
    __syncthreads();
    s[t] += add;
    __syncthreads();
  }
  boff[t] = s[t] - v;  // exclusive
  if (t == 255) offs[NN] = s[255];
}

__global__ __launch_bounds__(128) void k_scanC(const int* __restrict__ counts,
                                               const int* __restrict__ boff,
                                               int* __restrict__ offs,
                                               float* __restrict__ dinv) {
  int b = blockIdx.x, t = threadIdx.x;
  int v = counts[b * 128 + t];
  __shared__ int s[128];
  s[t] = v;
  __syncthreads();
  for (int o = 1; o < 128; o <<= 1) {
    int add = (t >= o) ? s[t - o] : 0;
    __syncthreads();
    s[t] += add;
    __syncthreads();
  }
  offs[b * 128 + t] = boff[b] + s[t] - v;
  dinv[b * 128 + t] = rsqrtf((float)(v + 1));
}

__global__ void k_fill(const int* __restrict__ ei, const int* __restrict__ offs,
                       int* __restrict__ cursor, int* __restrict__ csr) {
  int e = blockIdx.x * 256 + threadIdx.x;
  if (e < NE) {
    int d = ei[NE + e];
    int pos = offs[d] + atomicAdd(&cursor[d], 1);
    csr[pos] = ei[e];
  }
}

__global__ void k_starts(const int* __restrict__ batch, int* __restrict__ starts) {
  int g = threadIdx.x;
  int lo = 0, hi = NN;
  while (lo < hi) {
    int mid = (lo + hi) >> 1;
    if (batch[mid] < g) lo = mid + 1; else hi = mid;
  }
  starts[g] = lo;
  if (g == 0) starts[NG] = NN;
}

// ---------------- conversions / weight prep ----------------

__global__ void k_half(const float* __restrict__ src, f16* __restrict__ dst) {
  int i = (blockIdx.x * 256 + threadIdx.x) << 2;
  float4 v = *(const float4*)(src + i);
  f16x4 h = {(f16)v.x, (f16)v.y, (f16)v.z, (f16)v.w};
  *(f16x4*)(dst + i) = h;
}

// transpose split: src [K][N] fp32 -> dst [N][K] bf16 hi/lo
__global__ void k_split_t(const float* __restrict__ src, u16* __restrict__ hi, u16* __restrict__ lo,
                          int K, int N, int total) {
  int idx = blockIdx.x * 256 + threadIdx.x;
  if (idx >= total) return;
  int k = idx / N, n = idx - k * N;
  u16 h, l;
  split2(src[idx], h, l);
  size_t d = (size_t)n * K + k;
  hi[d] = h; lo[d] = l;
}

// combined gates weight: wg[n][c] = (c<512 ? W_ih[n][c]+W_hh[n][c] : W_ih[n][c]), split hi/lo
__global__ void k_wc(const float* __restrict__ W_ih, const float* __restrict__ W_hh,
                     u16* __restrict__ wghi, u16* __restrict__ wglo) {
  int idx = blockIdx.x * 256 + threadIdx.x;  // 2048*1024
  int n = idx >> 10, c = idx & 1023;
  float v = W_ih[(size_t)n * 1024 + c];
  if (c < 512) v += W_hh[(size_t)n * 512 + c];
  u16 h, l;
  split2(v, h, l);
  wghi[idx] = h; wglo[idx] = l;
}

// ---------------- split-bf16 MFMA GEMM, counted-vmcnt double-buffer (T3+T4 minimum) ----------------
// C[M][N] = A[M][K'] @ Bt[N][K']^T over K elems at koff = slice*K (split-K).
// 128x128 tile, BK=32, dbuf 2x32KB (64KB total -> 2 blocks/CU). Per K-step:
//   STAGE(next) [8 gload_lds] ; s_waitcnt vmcnt(8)  <- waits OLD tile only, new 8 stay in flight
//   s_barrier ; ds_read+MFMA(cur) ; s_barrier
// MODE 0: fp32 C partial at slice*M*N. MODE 1: +bias, relu, split->Chi/Clo. MODE 2: f16 out.
template <int MODE>
__global__ __launch_bounds__(256) void k_mfma_gemm(
    const u16* __restrict__ Ahi, const u16* __restrict__ Alo,
    const u16* __restrict__ Bhi, const u16* __restrict__ Blo,
    float* __restrict__ C, u16* __restrict__ Chi, u16* __restrict__ Clo,
    f16* __restrict__ Cf16, const float* __restrict__ bias,
    int M, int N, int K, int lda, int ldb) {
  __shared__ char lds[65536];  // 2 bufs x (Ahi 8K | Alo 8K | Bhi 8K | Blo 8K)

  int nbn = N >> 7;
  int nwg = (M >> 7) * nbn;
  int b = blockIdx.x;
  int slice = b / nwg;
  b -= slice * nwg;
  int koff = slice * K;
  int swz = (b & 7) * (nwg >> 3) + (b >> 3);  // nwg % 8 == 0 for all our shapes
  int bn = (swz % nbn) << 7;
  int bm = (swz / nbn) << 7;

  int tid = threadIdx.x;
  int w = tid >> 6, lane = tid & 63;
  int wm = (w >> 1) << 6, wn = (w & 1) << 6;
  int fr = lane & 15;
  int fq = lane >> 4;

  f32x4 acc[4][4];
#pragma unroll
  for (int i = 0; i < 4; ++i)
#pragma unroll
    for (int j = 0; j < 4; ++j) acc[i][j] = (f32x4){0.f, 0.f, 0.f, 0.f};

  auto STAGE = [&](int buf, int ks) {
#pragma unroll
    for (int i = 0; i < 2; ++i) {
      int L = i * 256 + tid;
      int row = L >> 2;                           // 0..127 (i=0: 0..63, i=1: 64..127)
      int ke = ((L & 3) ^ ((row >> 1) & 3)) << 3; // pre-swizzled global source
      int ldsoff = buf * 32768 + i * 4096 + w * 1024;  // wave-uniform (+lane*16 by HW)
      gload16(Ahi + (size_t)(bm + row) * lda + koff + ks + ke, lds + ldsoff);
      gload16(Alo + (size_t)(bm + row) * lda + koff + ks + ke, lds + 8192 + ldsoff);
      gload16(Bhi + (size_t)(bn + row) * ldb + koff + ks + ke, lds + 16384 + ldsoff);
      gload16(Blo + (size_t)(bn + row) * ldb + koff + ks + ke, lds + 24576 + ldsoff);
    }
  };

  int nt = K >> 5;
  STAGE(0, 0);
  int cur = 0;
  for (int t = 0; t < nt; ++t) {
    if (t + 1 < nt) {
      STAGE(cur ^ 1, (t + 1) << 5);
      asm volatile("s_waitcnt vmcnt(8)" ::: "memory");  // old tile landed; 8 new in flight
    } else {
      asm volatile("s_waitcnt vmcnt(0)" ::: "memory");
    }
    __builtin_amdgcn_s_barrier();   // all waves: buf[cur] valid
    const char* base = lds + cur * 32768;
    short8 ah[4], al[4], bh[4], bl[4];
#pragma unroll
    for (int m = 0; m < 4; ++m) {
      int row = wm + m * 16 + fr;
      int boff = row * 64 + ((fq ^ ((row >> 1) & 3)) << 4);
      ah[m] = *(const short8*)(base + boff);
      al[m] = *(const short8*)(base + 8192 + boff);
    }
#pragma unroll
    for (int n = 0; n < 4; ++n) {
      int row = wn + n * 16 + fr;
      int boff = row * 64 + ((fq ^ ((row >> 1) & 3)) << 4);
      bh[n] = *(const short8*)(base + 16384 + boff);
      bl[n] = *(const short8*)(base + 24576 + boff);
    }
#pragma unroll
    for (int m = 0; m < 4; ++m)
#pragma unroll
      for (int n = 0; n < 4; ++n) {
        acc[m][n] = __builtin_amdgcn_mfma_f32_16x16x32_bf16(ah[m], bh[n], acc[m][n], 0, 0, 0);
        acc[m][n] = __builtin_amdgcn_mfma_f32_16x16x32_bf16(ah[m], bl[n], acc[m][n], 0, 0, 0);
        acc[m][n] = __builtin_amdgcn_mfma_f32_16x16x32_bf16(al[m], bh[n], acc[m][n], 0, 0, 0);
      }
    __builtin_amdgcn_s_barrier();   // all waves done reading buf[cur]; next STAGE may overwrite
    cur ^= 1;
  }
#pragma unroll
  for (int m = 0; m < 4; ++m)
#pragma unroll
    for (int n = 0; n < 4; ++n)
#pragma unroll
      for (int i = 0; i < 4; ++i) {
        int r = bm + wm + m * 16 + fq * 4 + i;
        int c = bn + wn + n * 16 + fr;
        float val = acc[m][n][i];
        if (MODE == 1) {
          val += bias[c];
          val = fmaxf(val, 0.f);
          u16 h, l;
          split2(val, h, l);
          Chi[(size_t)r * N + c] = h;
          Clo[(size_t)r * N + c] = l;
        } else if (MODE == 2) {
          Cf16[(size_t)r * N + c] = (f16)val;
        } else {
          C[(size_t)slice * M * N + (size_t)r * N + c] = val;
        }
      }
}

// ---------------- aggregation, 256-dim fp16 -> bf16 hi/lo. One wave per node, ILP-4. ----------------
__global__ __launch_bounds__(256) void k_agg256(const f16* __restrict__ xh,
                                                const int* __restrict__ offs,
                                                const int* __restrict__ csr,
                                                const float* __restrict__ dinv,
                                                u16* __restrict__ ohi, u16* __restrict__ olo) {
  int wv = threadIdx.x >> 6, lane = threadIdx.x & 63;
  int v = blockIdx.x * 4 + wv;
  int f = lane << 2;
  int s = offs[v], t = offs[v + 1];
  float dv = dinv[v];
  float a0[4] = {}, a1[4] = {}, a2[4] = {}, a3[4] = {};
  for (int base = s; base < t; base += 64) {
    int rem = min(64, t - base);
    int idx = (lane < rem) ? csr[base + lane] : 0;
    float wl = (lane < rem) ? dinv[idx] : 0.f;
    int i = 0;
    for (; i + 3 < rem; i += 4) {
      int u0 = __shfl(idx, i), u1 = __shfl(idx, i + 1);
      int u2 = __shfl(idx, i + 2), u3 = __shfl(idx, i + 3);
      float w0 = __shfl(wl, i), w1 = __shfl(wl, i + 1);
      float w2 = __shfl(wl, i + 2), w3 = __shfl(wl, i + 3);
      f16x4 r0 = *(const f16x4*)(xh + (size_t)u0 * DIN + f);
      f16x4 r1 = *(const f16x4*)(xh + (size_t)u1 * DIN + f);
      f16x4 r2 = *(const f16x4*)(xh + (size_t)u2 * DIN + f);
      f16x4 r3 = *(const f16x4*)(xh + (size_t)u3 * DIN + f);
#pragma unroll
      for (int k = 0; k < 4; ++k) {
        a0[k] += w0 * (float)r0[k]; a1[k] += w1 * (float)r1[k];
        a2[k] += w2 * (float)r2[k]; a3[k] += w3 * (float)r3[k];
      }
    }
    for (; i < rem; ++i) {
      int u0 = __shfl(idx, i);
      float w0 = __shfl(wl, i);
      f16x4 r0 = *(const f16x4*)(xh + (size_t)u0 * DIN + f);
#pragma unroll
      for (int k = 0; k < 4; ++k) a0[k] += w0 * (float)r0[k];
    }
  }
  f16x4 rs = *(const f16x4*)(xh + (size_t)v * DIN + f);
  u16 h[4], l[4];
#pragma unroll
  for (int k = 0; k < 4; ++k) {
    float r = (a0[k] + a1[k] + a2[k] + a3[k] + dv * (float)rs[k]) * dv;
    split2(r, h[k], l[k]);
  }
  uint2 vh = {(unsigned)h[0] | ((unsigned)h[1] << 16), (unsigned)h[2] | ((unsigned)h[3] << 16)};
  uint2 vl = {(unsigned)l[0] | ((unsigned)l[1] << 16), (unsigned)l[2] | ((unsigned)l[3] << 16)};
  *(uint2*)(ohi + (size_t)v * DIN + f) = vh;
  *(uint2*)(olo + (size_t)v * DIN + f) = vl;
}

// ---------------- aggregation, 512-dim fp16 + bias -> fp16. One wave per node, ILP-4. ----------------
__global__ __launch_bounds__(256) void k_agg512(const f16* __restrict__ T2,
                                                const int* __restrict__ offs,
                                                const int* __restrict__ csr,
                                                const float* __restrict__ dinv,
                                                const float* __restrict__ bias,
                                                f16* __restrict__ H2) {
  int wv = threadIdx.x >> 6, lane = threadIdx.x & 63;
  int v = blockIdx.x * 4 + wv;
  int f = lane << 3;
  int s = offs[v], t = offs[v + 1];
  float dv = dinv[v];
  float a0[8] = {}, a1[8] = {}, a2[8] = {}, a3[8] = {};
  for (int base = s; base < t; base += 64) {
    int rem = min(64, t - base);
    int idx = (lane < rem) ? csr[base + lane] : 0;
    float wl = (lane < rem) ? dinv[idx] : 0.f;
    int i = 0;
    for (; i + 3 < rem; i += 4) {
      int u0 = __shfl(idx, i), u1 = __shfl(idx, i + 1);
      int u2 = __shfl(idx, i + 2), u3 = __shfl(idx, i + 3);
      float w0 = __shfl(wl, i), w1 = __shfl(wl, i + 1);
      float w2 = __shfl(wl, i + 2), w3 = __shfl(wl, i + 3);
      f16x8 r0 = *(const f16x8*)(T2 + (size_t)u0 * DH + f);
      f16x8 r1 = *(const f16x8*)(T2 + (size_t)u1 * DH + f);
      f16x8 r2 = *(const f16x8*)(T2 + (size_t)u2 * DH + f);
      f16x8 r3 = *(const f16x8*)(T2 + (size_t)u3 * DH + f);
#pragma unroll
      for (int k = 0; k < 8; ++k) {
        a0[k] += w0 * (float)r0[k]; a1[k] += w1 * (float)r1[k];
        a2[k] += w2 * (float)r2[k]; a3[k] += w3 * (float)r3[k];
      }
    }
    for (; i < rem; ++i) {
      int u0 = __shfl(idx, i);
      float w0 = __shfl(wl, i);
      f16x8 r0 = *(const f16x8*)(T2 + (size_t)u0 * DH + f);
#pragma unroll
      for (int k = 0; k < 8; ++k) a0[k] += w0 * (float)r0[k];
    }
  }
  f16x8 rs = *(const f16x8*)(T2 + (size_t)v * DH + f);
  float4 bb0 = *(const float4*)(bias + f);
  float4 bb1 = *(const float4*)(bias + f + 4);
  float bbv[8] = {bb0.x, bb0.y, bb0.z, bb0.w, bb1.x, bb1.y, bb1.z, bb1.w};
  f16x8 out;
#pragma unroll
  for (int k = 0; k < 8; ++k)
    out[k] = (f16)((a0[k] + a1[k] + a2[k] + a3[k] + dv * (float)rs[k]) * dv + bbv[k]);
  *(f16x8*)(H2 + (size_t)v * DH + f) = out;
}

// ---------------- fused set2set step: LSTM (from 4 split-K partials) + flash pool ----------------
__global__ __launch_bounds__(256) void k_step(const float* __restrict__ gp,
                                              const float* __restrict__ b_ih,
                                              const float* __restrict__ b_hh,
                                              float* __restrict__ cs,
                                              const f16* __restrict__ H2,
                                              const int* __restrict__ starts,
                                              float* __restrict__ qstar,
                                              u16* __restrict__ qhhi, u16* __restrict__ qhlo) {
  int g = blockIdx.x;
  int tid = threadIdx.x, wv = tid >> 6, lane = tid & 63;
  __shared__ float shs[512];
  __shared__ float lm[4], lsum[4];
  __shared__ float lr[4][512];

  const float* g0 = gp + (size_t)g * 2048;
#pragma unroll
  for (int jj = 0; jj < 2; ++jj) {
    int j = tid + jj * 256;
    float iv = b_ih[j]        + b_hh[j];
    float fv = b_ih[512 + j]  + b_hh[512 + j];
    float gv = b_ih[1024 + j] + b_hh[1024 + j];
    float ov = b_ih[1536 + j] + b_hh[1536 + j];
#pragma unroll
    for (int sl = 0; sl < 4; ++sl) {
      const float* gs = g0 + (size_t)sl * 524288;
      iv += gs[j]; fv += gs[512 + j]; gv += gs[1024 + j]; ov += gs[1536 + j];
    }
    float si = 1.f / (1.f + expf(-iv));
    float sf = 1.f / (1.f + expf(-fv));
    float so = 1.f / (1.f + expf(-ov));
    float c = sf * cs[(size_t)g * 512 + j] + si * tanhf(gv);
    float h = so * tanhf(c);
    cs[(size_t)g * 512 + j] = c;
    shs[j] = h;
    qstar[(size_t)g * 1024 + j] = h;
    u16 hh, hl;
    split2(h, hh, hl);
    qhhi[(size_t)g * 1024 + j] = hh;
    qhlo[(size_t)g * 1024 + j] = hl;
  }
  __syncthreads();

  int s = starts[g], t = starts[g + 1];
  int cnt = t - s;
  float hsr[8];
#pragma unroll
  for (int k = 0; k < 8; ++k) hsr[k] = shs[lane * 8 + k];

  float m = -INFINITY, ssum = 0.f;
  float racc[8] = {};
  for (int i = wv; i < cnt; i += 4) {
    f16x8 rv = *(const f16x8*)(H2 + (size_t)(s + i) * DH + lane * 8);
    float e = 0.f;
#pragma unroll
    for (int k = 0; k < 8; ++k) e += (float)rv[k] * hsr[k];
#pragma unroll
    for (int o = 1; o < 64; o <<= 1) e += __shfl_xor(e, o);
    float mn = fmaxf(m, e);
    float scale = expf(m - mn);   // first iter: exp(-inf)=0
    float p = expf(e - mn);
    ssum = ssum * scale + p;
#pragma unroll
    for (int k = 0; k < 8; ++k) racc[k] = racc[k] * scale + p * (float)rv[k];
    m = mn;
  }
  if (lane == 0) { lm[wv] = m; lsum[wv] = ssum; }
#pragma unroll
  for (int k = 0; k < 8; ++k) lr[wv][lane * 8 + k] = racc[k];
  __syncthreads();
  float M = fmaxf(fmaxf(lm[0], lm[1]), fmaxf(lm[2], lm[3]));
  if (!(M > -3.0e38f)) M = 0.f;  // empty graph
  float sc0 = expf(lm[0] - M), sc1 = expf(lm[1] - M);
  float sc2 = expf(lm[2] - M), sc3 = expf(lm[3] - M);
  float denom = lsum[0] * sc0 + lsum[1] * sc1 + lsum[2] * sc2 + lsum[3] * sc3;
  float inv = 1.f / fmaxf(denom, 1e-12f);
  int f = tid << 1;
  float r0 = (lr[0][f] * sc0 + lr[1][f] * sc1 + lr[2][f] * sc2 + lr[3][f] * sc3) * inv;
  float r1 = (lr[0][f + 1] * sc0 + lr[1][f + 1] * sc1 + lr[2][f + 1] * sc2 + lr[3][f + 1] * sc3) * inv;
  qstar[(size_t)g * 1024 + 512 + f] = r0;
  qstar[(size_t)g * 1024 + 513 + f] = r1;
  u16 h0, l0, h1, l1;
  split2(r0, h0, l0); split2(r1, h1, l1);
  size_t q = (size_t)g * 1024 + 512 + f;
  qhhi[q] = h0;     qhlo[q] = l0;
  qhhi[q + 1] = h1; qhlo[q + 1] = l1;
}

// ---------------- launch ----------------
extern "C" void kernel_launch(void* const* d_in, const int* in_sizes, int n_in,
                              void* d_out, int out_size, void* d_ws, size_t ws_size,
                              hipStream_t stream) {
  const float* x     = (const float*)d_in[0];
  const int*   ei    = (const int*)d_in[1];
  const int*   batch = (const int*)d_in[2];
  const float* W1    = (const float*)d_in[3];
  const float* b1    = (const float*)d_in[4];
  const float* W2    = (const float*)d_in[5];
  const float* b2    = (const float*)d_in[6];
  const float* W_ih  = (const float*)d_in[7];
  const float* W_hh  = (const float*)d_in[8];
  const float* b_ih  = (const float*)d_in[9];
  const float* b_hh  = (const float*)d_in[10];
  float* qstar = (float*)d_out;

  char* w = (char*)d_ws;
  size_t off = 0;
  auto carve = [&](size_t bytes) -> void* {
    void* p = w + off;
    off += (bytes + 255) & ~(size_t)255;
    return p;
  };
  f16* xh      = (f16*)carve((size_t)NN * DIN * 2);
  u16* axhi    = (u16*)carve((size_t)NN * DIN * 2);
  u16* axlo    = (u16*)carve((size_t)NN * DIN * 2);
  u16* h1hi    = (u16*)carve((size_t)NN * DH * 2);
  u16* h1lo    = (u16*)carve((size_t)NN * DH * 2);
  f16* t2h     = (f16*)carve((size_t)NN * DH * 2);
  f16* H2h     = (f16*)carve((size_t)NN * DH * 2);
  u16* w1thi   = (u16*)carve((size_t)DH * DIN * 2);
  u16* w1tlo   = (u16*)carve((size_t)DH * DIN * 2);
  u16* w2thi   = (u16*)carve((size_t)DH * DH * 2);
  u16* w2tlo   = (u16*)carve((size_t)DH * DH * 2);
  u16* wghi    = (u16*)carve((size_t)2048 * 1024 * 2);
  u16* wglo    = (u16*)carve((size_t)2048 * 1024 * 2);
  u16* qhhi    = (u16*)carve((size_t)NG * 1024 * 2);
  u16* qhlo    = (u16*)carve((size_t)NG * 1024 * 2);
  float* gp    = (float*)carve((size_t)4 * NG * 2048 * 4);
  int* counts  = (int*)carve((size_t)NN * 4);
  int* offs    = (int*)carve((size_t)(NN + 1) * 4);
  int* cursor  = (int*)carve((size_t)NN * 4);
  int* csr     = (int*)carve((size_t)NE * 4);
  float* dinv  = (float*)carve((size_t)NN * 4);
  float* cs    = (float*)carve((size_t)NG * DOUT * 4);
  int* starts  = (int*)carve((size_t)(NG + 1) * 4);
  int* bsum    = (int*)carve((size_t)256 * 4);
  int* boff    = (int*)carve((size_t)256 * 4);

  hipMemsetAsync(counts, 0, (size_t)NN * 4, stream);
  hipMemsetAsync(cursor, 0, (size_t)NN * 4, stream);
  hipMemsetAsync(cs, 0, (size_t)NG * DOUT * 4, stream);
  hipMemsetAsync(qstar, 0, (size_t)NG * 1024 * 4, stream);
  hipMemsetAsync(qhhi, 0, (size_t)NG * 1024 * 2, stream);
  hipMemsetAsync(qhlo, 0, (size_t)NG * 1024 * 2, stream);

  k_count<<<NE / 256, 256, 0, stream>>>(ei, counts);
  k_scanA<<<NN / 128, 128, 0, stream>>>(counts, bsum);
  k_scanB<<<1, 256, 0, stream>>>(bsum, boff, offs);
  k_scanC<<<NN / 128, 128, 0, stream>>>(counts, boff, offs, dinv);
  k_fill<<<NE / 256, 256, 0, stream>>>(ei, offs, cursor, csr);
  k_starts<<<1, NG, 0, stream>>>(batch, starts);

  k_half<<<NN * DIN / 1024, 256, 0, stream>>>(x, xh);
  k_split_t<<<(DIN * DH + 255) / 256, 256, 0, stream>>>(W1, w1thi, w1tlo, DIN, DH, DIN * DH);
  k_split_t<<<(DH * DH + 255) / 256, 256, 0, stream>>>(W2, w2thi, w2tlo, DH, DH, DH * DH);
  k_wc<<<(2048 * 1024) / 256, 256, 0, stream>>>(W_ih, W_hh, wghi, wglo);

  // layer 1: aggx = Agg(x) ; H1 = relu(aggx@W1 + b1)
  k_agg256<<<NN / 4, 256, 0, stream>>>(xh, offs, csr, dinv, axhi, axlo);
  k_mfma_gemm<1><<<(NN / 128) * (DH / 128), 256, 0, stream>>>(
      axhi, axlo, w1thi, w1tlo, nullptr, h1hi, h1lo, nullptr, b1, NN, DH, DIN, DIN, DIN);
  // layer 2: t2 = H1@W2 ; H2 = Agg(t2) + b2
  k_mfma_gemm<2><<<(NN / 128) * (DH / 128), 256, 0, stream>>>(
      h1hi, h1lo, w2thi, w2tlo, nullptr, nullptr, nullptr, t2h, nullptr, NN, DH, DH, DH, DH);
  k_agg512<<<NN / 4, 256, 0, stream>>>(t2h, offs, csr, dinv, b2, H2h);

  for (int step = 0; step < 3; ++step) {
    // gates partials: 4 K-slices of 256 in one dispatch (grid 128)
    k_mfma_gemm<0><<<4 * (NG / 128) * (2048 / 128), 256, 0, stream>>>(
        qhhi, qhlo, wghi, wglo, gp, nullptr, nullptr, nullptr, nullptr,
        NG, 2048, 256, 1024, 1024);
    k_step<<<NG, 256, 0, stream>>>(gp, b_ih, b_hh, cs, H2h, starts, qstar, qhhi, qhlo);
  }
}

// Round 8
// 322.681 us; speedup vs baseline: 1.0743x; 1.0743x over previous
//
#include <hip/hip_runtime.h>
#include <math.h>

#define NN 32768
#define NE 262144
#define NG 256
#define DIN 256
#define DH 512
#define DOUT 512

typedef unsigned short u16;
typedef _Float16 f16;
typedef __attribute__((ext_vector_type(4))) _Float16 f16x4;
typedef __attribute__((ext_vector_type(8))) _Float16 f16x8;
typedef __attribute__((ext_vector_type(4))) float f32x4;

__device__ inline void split2h(float f, f16& h, f16& l) {
  h = (f16)f;
  l = (f16)(f - (float)h);
}

__device__ inline void gload16(const void* g, void* l) {
  __builtin_amdgcn_global_load_lds((const __attribute__((address_space(1))) unsigned int*)g,
                                   (__attribute__((address_space(3))) unsigned int*)l,
                                   16, 0, 0);
}

// ---------------- graph prep ----------------

__global__ void k_count(const int* __restrict__ ei, int* __restrict__ counts) {
  int e = blockIdx.x * 256 + threadIdx.x;
  if (e < NE) atomicAdd(&counts[ei[NE + e]], 1);
}

// hierarchical scan: A) per-block reduce, B) scan of block sums, C) apply + local scan + dinv
__global__ __launch_bounds__(128) void k_scanA(const int* __restrict__ counts,
                                               int* __restrict__ bsum) {
  int b = blockIdx.x, t = threadIdx.x;
  int v = counts[b * 128 + t];
  __shared__ int red[128];
  red[t] = v;
  __syncthreads();
#pragma unroll
  for (int o = 64; o > 0; o >>= 1) {
    if (t < o) red[t] += red[t + o];
    __syncthreads();
  }
  if (t == 0) bsum[b] = red[0];
}

__global__ __launch_bounds__(256) void k_scanB(const int* __restrict__ bsum,
                                               int* __restrict__ boff,
                                               int* __restrict__ offs) {
  __shared__ int s[256];
  int t = threadIdx.x;
  int v = bsum[t];
  s[t] = v;
  __syncthreads();
  for (int o = 1; o < 256; o <<= 1) {
    int add = (t >= o) ? s[t - o] : 0;
    __syncthreads();
    s[t] += add;
    __syncthreads();
  }
  boff[t] = s[t] - v;  // exclusive
  if (t == 255) offs[NN] = s[255];
}

__global__ __launch_bounds__(128) void k_scanC(const int* __restrict__ counts,
                                               const int* __restrict__ boff,
                                               int* __restrict__ offs,
                                               float* __restrict__ dinv) {
  int b = blockIdx.x, t = threadIdx.x;
  int v = counts[b * 128 + t];
  __shared__ int s[128];
  s[t] = v;
  __syncthreads();
  for (int o = 1; o < 128; o <<= 1) {
    int add = (t >= o) ? s[t - o] : 0;
    __syncthreads();
    s[t] += add;
    __syncthreads();
  }
  offs[b * 128 + t] = boff[b] + s[t] - v;
  dinv[b * 128 + t] = rsqrtf((float)(v + 1));
}

__global__ void k_fill(const int* __restrict__ ei, const int* __restrict__ offs,
                       int* __restrict__ cursor, int* __restrict__ csr) {
  int e = blockIdx.x * 256 + threadIdx.x;
  if (e < NE) {
    int d = ei[NE + e];
    int pos = offs[d] + atomicAdd(&cursor[d], 1);
    csr[pos] = ei[e];
  }
}

__global__ void k_starts(const int* __restrict__ batch, int* __restrict__ starts) {
  int g = threadIdx.x;
  int lo = 0, hi = NN;
  while (lo < hi) {
    int mid = (lo + hi) >> 1;
    if (batch[mid] < g) lo = mid + 1; else hi = mid;
  }
  starts[g] = lo;
  if (g == 0) starts[NG] = NN;
}

// ---------------- conversions / weight prep ----------------

__global__ void k_half(const float* __restrict__ src, f16* __restrict__ dst) {
  int i = (blockIdx.x * 256 + threadIdx.x) << 2;
  float4 v = *(const float4*)(src + i);
  f16x4 h = {(f16)v.x, (f16)v.y, (f16)v.z, (f16)v.w};
  *(f16x4*)(dst + i) = h;
}

// transpose + fp16: src [K][N] fp32 -> dst [N][K] f16
__global__ void k_split_th(const float* __restrict__ src, f16* __restrict__ dst,
                           int K, int N, int total) {
  int idx = blockIdx.x * 256 + threadIdx.x;
  if (idx >= total) return;
  int k = idx / N, n = idx - k * N;
  dst[(size_t)n * K + k] = (f16)src[idx];
}

// combined gates weight: wg[n][c] = (c<512 ? W_ih[n][c]+W_hh[n][c] : W_ih[n][c]), f16
__global__ void k_wc(const float* __restrict__ W_ih, const float* __restrict__ W_hh,
                     f16* __restrict__ wgh) {
  int idx = blockIdx.x * 256 + threadIdx.x;  // 2048*1024
  int n = idx >> 10, c = idx & 1023;
  float v = W_ih[(size_t)n * 1024 + c];
  if (c < 512) v += W_hh[(size_t)n * 512 + c];
  wgh[idx] = (f16)v;
}

// ---------------- split-fp16 MFMA GEMM (BK=64 single-buffer, m97 2-barrier structure) ----------------
// C = (Ahi+Alo) @ Bhi^T : 2 MFMAs per product (ah*bh + al*bh); B rounding 2^-11 is the only error.
// 128x128 tile, 48KB LDS (3 stages) -> 3 blocks/CU. Split-K via slice = blockIdx / nwg.
// MODE 0: fp32 C partial at slice*M*N. MODE 1: +bias, relu, split->Chi/Clo (f16). MODE 2: f16 out.
template <int MODE>
__global__ __launch_bounds__(256) void k_mfma_gemm(
    const f16* __restrict__ Ahi, const f16* __restrict__ Alo,
    const f16* __restrict__ Bhi,
    float* __restrict__ C, f16* __restrict__ Chi, f16* __restrict__ Clo,
    f16* __restrict__ Cf16, const float* __restrict__ bias,
    int M, int N, int K, int lda, int ldb) {
  __shared__ char lds[49152];  // Ahi 16K | Alo 16K | Bhi 16K

  int nbn = N >> 7;
  int nwg = (M >> 7) * nbn;
  int b = blockIdx.x;
  int slice = b / nwg;
  b -= slice * nwg;
  int koff = slice * K;
  int swz = (b & 7) * (nwg >> 3) + (b >> 3);  // nwg % 8 == 0 for all our shapes
  int bn = (swz % nbn) << 7;
  int bm = (swz / nbn) << 7;

  int tid = threadIdx.x;
  int w = tid >> 6, lane = tid & 63;
  int wm = (w >> 1) << 6, wn = (w & 1) << 6;
  int fr = lane & 15;
  int fq = lane >> 4;

  f32x4 acc[4][4];
#pragma unroll
  for (int i = 0; i < 4; ++i)
#pragma unroll
    for (int j = 0; j < 4; ++j) acc[i][j] = (f32x4){0.f, 0.f, 0.f, 0.f};

  for (int ks = 0; ks < K; ks += 64) {
#pragma unroll
    for (int i = 0; i < 4; ++i) {
      int L = i * 256 + tid;
      int row = L >> 3;
      int ke = ((L & 7) ^ (row & 7)) << 3;  // pre-swizzled global source
      int ldsoff = i * 4096 + w * 1024;     // wave-uniform base (+lane*16 by HW)
      gload16(Ahi + (size_t)(bm + row) * lda + koff + ks + ke, lds + ldsoff);
      gload16(Alo + (size_t)(bm + row) * lda + koff + ks + ke, lds + 16384 + ldsoff);
      gload16(Bhi + (size_t)(bn + row) * ldb + koff + ks + ke, lds + 32768 + ldsoff);
    }
    __syncthreads();
#pragma unroll
    for (int kk = 0; kk < 2; ++kk) {
      f16x8 ah[4], al[4], bh[4];
#pragma unroll
      for (int m = 0; m < 4; ++m) {
        int row = wm + m * 16 + fr;
        int boff = row * 128 + (((kk << 6) + (fq << 4)) ^ ((row & 7) << 4));
        ah[m] = *(const f16x8*)(lds + boff);
        al[m] = *(const f16x8*)(lds + 16384 + boff);
      }
#pragma unroll
      for (int n = 0; n < 4; ++n) {
        int row = wn + n * 16 + fr;
        int boff = row * 128 + (((kk << 6) + (fq << 4)) ^ ((row & 7) << 4));
        bh[n] = *(const f16x8*)(lds + 32768 + boff);
      }
#pragma unroll
      for (int m = 0; m < 4; ++m)
#pragma unroll
        for (int n = 0; n < 4; ++n) {
          acc[m][n] = __builtin_amdgcn_mfma_f32_16x16x32_f16(ah[m], bh[n], acc[m][n], 0, 0, 0);
          acc[m][n] = __builtin_amdgcn_mfma_f32_16x16x32_f16(al[m], bh[n], acc[m][n], 0, 0, 0);
        }
    }
    __syncthreads();
  }
#pragma unroll
  for (int m = 0; m < 4; ++m)
#pragma unroll
    for (int n = 0; n < 4; ++n)
#pragma unroll
      for (int i = 0; i < 4; ++i) {
        int r = bm + wm + m * 16 + fq * 4 + i;
        int c = bn + wn + n * 16 + fr;
        float val = acc[m][n][i];
        if (MODE == 1) {
          val += bias[c];
          val = fmaxf(val, 0.f);
          f16 h, l;
          split2h(val, h, l);
          Chi[(size_t)r * N + c] = h;
          Clo[(size_t)r * N + c] = l;
        } else if (MODE == 2) {
          Cf16[(size_t)r * N + c] = (f16)val;
        } else {
          C[(size_t)slice * M * N + (size_t)r * N + c] = val;
        }
      }
}

// ---------------- aggregation, 256-dim fp16 -> f16 hi/lo. One wave per node, ILP-4. ----------------
__global__ __launch_bounds__(256) void k_agg256(const f16* __restrict__ xh,
                                                const int* __restrict__ offs,
                                                const int* __restrict__ csr,
                                                const float* __restrict__ dinv,
                                                f16* __restrict__ ohi, f16* __restrict__ olo) {
  int wv = threadIdx.x >> 6, lane = threadIdx.x & 63;
  int v = blockIdx.x * 4 + wv;
  int f = lane << 2;
  int s = offs[v], t = offs[v + 1];
  float dv = dinv[v];
  float a0[4] = {}, a1[4] = {}, a2[4] = {}, a3[4] = {};
  for (int base = s; base < t; base += 64) {
    int rem = min(64, t - base);
    int idx = (lane < rem) ? csr[base + lane] : 0;
    float wl = (lane < rem) ? dinv[idx] : 0.f;
    int i = 0;
    for (; i + 3 < rem; i += 4) {
      int u0 = __shfl(idx, i), u1 = __shfl(idx, i + 1);
      int u2 = __shfl(idx, i + 2), u3 = __shfl(idx, i + 3);
      float w0 = __shfl(wl, i), w1 = __shfl(wl, i + 1);
      float w2 = __shfl(wl, i + 2), w3 = __shfl(wl, i + 3);
      f16x4 r0 = *(const f16x4*)(xh + (size_t)u0 * DIN + f);
      f16x4 r1 = *(const f16x4*)(xh + (size_t)u1 * DIN + f);
      f16x4 r2 = *(const f16x4*)(xh + (size_t)u2 * DIN + f);
      f16x4 r3 = *(const f16x4*)(xh + (size_t)u3 * DIN + f);
#pragma unroll
      for (int k = 0; k < 4; ++k) {
        a0[k] += w0 * (float)r0[k]; a1[k] += w1 * (float)r1[k];
        a2[k] += w2 * (float)r2[k]; a3[k] += w3 * (float)r3[k];
      }
    }
    for (; i < rem; ++i) {
      int u0 = __shfl(idx, i);
      float w0 = __shfl(wl, i);
      f16x4 r0 = *(const f16x4*)(xh + (size_t)u0 * DIN + f);
#pragma unroll
      for (int k = 0; k < 4; ++k) a0[k] += w0 * (float)r0[k];
    }
  }
  f16x4 rs = *(const f16x4*)(xh + (size_t)v * DIN + f);
  f16x4 vh, vl;
#pragma unroll
  for (int k = 0; k < 4; ++k) {
    float r = (a0[k] + a1[k] + a2[k] + a3[k] + dv * (float)rs[k]) * dv;
    f16 h, l;
    split2h(r, h, l);
    vh[k] = h; vl[k] = l;
  }
  *(f16x4*)(ohi + (size_t)v * DIN + f) = vh;
  *(f16x4*)(olo + (size_t)v * DIN + f) = vl;
}

// ---------------- aggregation, 512-dim fp16 + bias -> fp16. One wave per node, ILP-4. ----------------
__global__ __launch_bounds__(256) void k_agg512(const f16* __restrict__ T2,
                                                const int* __restrict__ offs,
                                                const int* __restrict__ csr,
                                                const float* __restrict__ dinv,
                                                const float* __restrict__ bias,
                                                f16* __restrict__ H2) {
  int wv = threadIdx.x >> 6, lane = threadIdx.x & 63;
  int v = blockIdx.x * 4 + wv;
  int f = lane << 3;
  int s = offs[v], t = offs[v + 1];
  float dv = dinv[v];
  float a0[8] = {}, a1[8] = {}, a2[8] = {}, a3[8] = {};
  for (int base = s; base < t; base += 64) {
    int rem = min(64, t - base);
    int idx = (lane < rem) ? csr[base + lane] : 0;
    float wl = (lane < rem) ? dinv[idx] : 0.f;
    int i = 0;
    for (; i + 3 < rem; i += 4) {
      int u0 = __shfl(idx, i), u1 = __shfl(idx, i + 1);
      int u2 = __shfl(idx, i + 2), u3 = __shfl(idx, i + 3);
      float w0 = __shfl(wl, i), w1 = __shfl(wl, i + 1);
      float w2 = __shfl(wl, i + 2), w3 = __shfl(wl, i + 3);
      f16x8 r0 = *(const f16x8*)(T2 + (size_t)u0 * DH + f);
      f16x8 r1 = *(const f16x8*)(T2 + (size_t)u1 * DH + f);
      f16x8 r2 = *(const f16x8*)(T2 + (size_t)u2 * DH + f);
      f16x8 r3 = *(const f16x8*)(T2 + (size_t)u3 * DH + f);
#pragma unroll
      for (int k = 0; k < 8; ++k) {
        a0[k] += w0 * (float)r0[k]; a1[k] += w1 * (float)r1[k];
        a2[k] += w2 * (float)r2[k]; a3[k] += w3 * (float)r3[k];
      }
    }
    for (; i < rem; ++i) {
      int u0 = __shfl(idx, i);
      float w0 = __shfl(wl, i);
      f16x8 r0 = *(const f16x8*)(T2 + (size_t)u0 * DH + f);
#pragma unroll
      for (int k = 0; k < 8; ++k) a0[k] += w0 * (float)r0[k];
    }
  }
  f16x8 rs = *(const f16x8*)(T2 + (size_t)v * DH + f);
  float4 bb0 = *(const float4*)(bias + f);
  float4 bb1 = *(const float4*)(bias + f + 4);
  float bbv[8] = {bb0.x, bb0.y, bb0.z, bb0.w, bb1.x, bb1.y, bb1.z, bb1.w};
  f16x8 out;
#pragma unroll
  for (int k = 0; k < 8; ++k)
    out[k] = (f16)((a0[k] + a1[k] + a2[k] + a3[k] + dv * (float)rs[k]) * dv + bbv[k]);
  *(f16x8*)(H2 + (size_t)v * DH + f) = out;
}

// ---------------- fused set2set step: LSTM (from 4 split-K partials) + flash pool ----------------
__global__ __launch_bounds__(256) void k_step(const float* __restrict__ gp,
                                              const float* __restrict__ b_ih,
                                              const float* __restrict__ b_hh,
                                              float* __restrict__ cs,
                                              const f16* __restrict__ H2,
                                              const int* __restrict__ starts,
                                              float* __restrict__ qstar,
                                              f16* __restrict__ qhhi, f16* __restrict__ qhlo) {
  int g = blockIdx.x;
  int tid = threadIdx.x, wv = tid >> 6, lane = tid & 63;
  __shared__ float shs[512];
  __shared__ float lm[4], lsum[4];
  __shared__ float lr[4][512];

  const float* g0 = gp + (size_t)g * 2048;
#pragma unroll
  for (int jj = 0; jj < 2; ++jj) {
    int j = tid + jj * 256;
    float iv = b_ih[j]        + b_hh[j];
    float fv = b_ih[512 + j]  + b_hh[512 + j];
    float gv = b_ih[1024 + j] + b_hh[1024 + j];
    float ov = b_ih[1536 + j] + b_hh[1536 + j];
#pragma unroll
    for (int sl = 0; sl < 4; ++sl) {
      const float* gs = g0 + (size_t)sl * 524288;
      iv += gs[j]; fv += gs[512 + j]; gv += gs[1024 + j]; ov += gs[1536 + j];
    }
    float si = 1.f / (1.f + expf(-iv));
    float sf = 1.f / (1.f + expf(-fv));
    float so = 1.f / (1.f + expf(-ov));
    float c = sf * cs[(size_t)g * 512 + j] + si * tanhf(gv);
    float h = so * tanhf(c);
    cs[(size_t)g * 512 + j] = c;
    shs[j] = h;
    qstar[(size_t)g * 1024 + j] = h;
    f16 hh, hl;
    split2h(h, hh, hl);
    qhhi[(size_t)g * 1024 + j] = hh;
    qhlo[(size_t)g * 1024 + j] = hl;
  }
  __syncthreads();

  int s = starts[g], t = starts[g + 1];
  int cnt = t - s;
  float hsr[8];
#pragma unroll
  for (int k = 0; k < 8; ++k) hsr[k] = shs[lane * 8 + k];

  float m = -INFINITY, ssum = 0.f;
  float racc[8] = {};
  for (int i = wv; i < cnt; i += 4) {
    f16x8 rv = *(const f16x8*)(H2 + (size_t)(s + i) * DH + lane * 8);
    float e = 0.f;
#pragma unroll
    for (int k = 0; k < 8; ++k) e += (float)rv[k] * hsr[k];
#pragma unroll
    for (int o = 1; o < 64; o <<= 1) e += __shfl_xor(e, o);
    float mn = fmaxf(m, e);
    float scale = expf(m - mn);   // first iter: exp(-inf)=0
    float p = expf(e - mn);
    ssum = ssum * scale + p;
#pragma unroll
    for (int k = 0; k < 8; ++k) racc[k] = racc[k] * scale + p * (float)rv[k];
    m = mn;
  }
  if (lane == 0) { lm[wv] = m; lsum[wv] = ssum; }
#pragma unroll
  for (int k = 0; k < 8; ++k) lr[wv][lane * 8 + k] = racc[k];
  __syncthreads();
  float M = fmaxf(fmaxf(lm[0], lm[1]), fmaxf(lm[2], lm[3]));
  if (!(M > -3.0e38f)) M = 0.f;  // empty graph
  float sc0 = expf(lm[0] - M), sc1 = expf(lm[1] - M);
  float sc2 = expf(lm[2] - M), sc3 = expf(lm[3] - M);
  float denom = lsum[0] * sc0 + lsum[1] * sc1 + lsum[2] * sc2 + lsum[3] * sc3;
  float inv = 1.f / fmaxf(denom, 1e-12f);
  int f = tid << 1;
  float r0 = (lr[0][f] * sc0 + lr[1][f] * sc1 + lr[2][f] * sc2 + lr[3][f] * sc3) * inv;
  float r1 = (lr[0][f + 1] * sc0 + lr[1][f + 1] * sc1 + lr[2][f + 1] * sc2 + lr[3][f + 1] * sc3) * inv;
  qstar[(size_t)g * 1024 + 512 + f] = r0;
  qstar[(size_t)g * 1024 + 513 + f] = r1;
  f16 h0, l0, h1, l1;
  split2h(r0, h0, l0); split2h(r1, h1, l1);
  size_t q = (size_t)g * 1024 + 512 + f;
  qhhi[q] = h0;     qhlo[q] = l0;
  qhhi[q + 1] = h1; qhlo[q + 1] = l1;
}

// ---------------- launch ----------------
extern "C" void kernel_launch(void* const* d_in, const int* in_sizes, int n_in,
                              void* d_out, int out_size, void* d_ws, size_t ws_size,
                              hipStream_t stream) {
  const float* x     = (const float*)d_in[0];
  const int*   ei    = (const int*)d_in[1];
  const int*   batch = (const int*)d_in[2];
  const float* W1    = (const float*)d_in[3];
  const float* b1    = (const float*)d_in[4];
  const float* W2    = (const float*)d_in[5];
  const float* b2    = (const float*)d_in[6];
  const float* W_ih  = (const float*)d_in[7];
  const float* W_hh  = (const float*)d_in[8];
  const float* b_ih  = (const float*)d_in[9];
  const float* b_hh  = (const float*)d_in[10];
  float* qstar = (float*)d_out;

  char* w = (char*)d_ws;
  size_t off = 0;
  auto carve = [&](size_t bytes) -> void* {
    void* p = w + off;
    off += (bytes + 255) & ~(size_t)255;
    return p;
  };
  f16* xh      = (f16*)carve((size_t)NN * DIN * 2);
  f16* axhi    = (f16*)carve((size_t)NN * DIN * 2);
  f16* axlo    = (f16*)carve((size_t)NN * DIN * 2);
  f16* h1hi    = (f16*)carve((size_t)NN * DH * 2);
  f16* h1lo    = (f16*)carve((size_t)NN * DH * 2);
  f16* t2h     = (f16*)carve((size_t)NN * DH * 2);
  f16* H2h     = (f16*)carve((size_t)NN * DH * 2);
  f16* w1th    = (f16*)carve((size_t)DH * DIN * 2);
  f16* w2th    = (f16*)carve((size_t)DH * DH * 2);
  f16* wgh     = (f16*)carve((size_t)2048 * 1024 * 2);
  f16* qhhi    = (f16*)carve((size_t)NG * 1024 * 2);
  f16* qhlo    = (f16*)carve((size_t)NG * 1024 * 2);
  float* gp    = (float*)carve((size_t)4 * NG * 2048 * 4);
  int* counts  = (int*)carve((size_t)NN * 4);
  int* offs    = (int*)carve((size_t)(NN + 1) * 4);
  int* cursor  = (int*)carve((size_t)NN * 4);
  int* csr     = (int*)carve((size_t)NE * 4);
  float* dinv  = (float*)carve((size_t)NN * 4);
  float* cs    = (float*)carve((size_t)NG * DOUT * 4);
  int* starts  = (int*)carve((size_t)(NG + 1) * 4);
  int* bsum    = (int*)carve((size_t)256 * 4);
  int* boff    = (int*)carve((size_t)256 * 4);

  hipMemsetAsync(counts, 0, (size_t)NN * 4, stream);
  hipMemsetAsync(cursor, 0, (size_t)NN * 4, stream);
  hipMemsetAsync(cs, 0, (size_t)NG * DOUT * 4, stream);
  hipMemsetAsync(qstar, 0, (size_t)NG * 1024 * 4, stream);
  hipMemsetAsync(qhhi, 0, (size_t)NG * 1024 * 2, stream);
  hipMemsetAsync(qhlo, 0, (size_t)NG * 1024 * 2, stream);

  k_count<<<NE / 256, 256, 0, stream>>>(ei, counts);
  k_scanA<<<NN / 128, 128, 0, stream>>>(counts, bsum);
  k_scanB<<<1, 256, 0, stream>>>(bsum, boff, offs);
  k_scanC<<<NN / 128, 128, 0, stream>>>(counts, boff, offs, dinv);
  k_fill<<<NE / 256, 256, 0, stream>>>(ei, offs, cursor, csr);
  k_starts<<<1, NG, 0, stream>>>(batch, starts);

  k_half<<<NN * DIN / 1024, 256, 0, stream>>>(x, xh);
  k_split_th<<<(DIN * DH + 255) / 256, 256, 0, stream>>>(W1, w1th, DIN, DH, DIN * DH);
  k_split_th<<<(DH * DH + 255) / 256, 256, 0, stream>>>(W2, w2th, DH, DH, DH * DH);
  k_wc<<<(2048 * 1024) / 256, 256, 0, stream>>>(W_ih, W_hh, wgh);

  // layer 1: aggx = Agg(x) ; H1 = relu(aggx@W1 + b1)
  k_agg256<<<NN / 4, 256, 0, stream>>>(xh, offs, csr, dinv, axhi, axlo);
  k_mfma_gemm<1><<<(NN / 128) * (DH / 128), 256, 0, stream>>>(
      axhi, axlo, w1th, nullptr, h1hi, h1lo, nullptr, b1, NN, DH, DIN, DIN, DIN);
  // layer 2: t2 = H1@W2 ; H2 = Agg(t2) + b2
  k_mfma_gemm<2><<<(NN / 128) * (DH / 128), 256, 0, stream>>>(
      h1hi, h1lo, w2th, nullptr, nullptr, nullptr, t2h, nullptr, NN, DH, DH, DH, DH);
  k_agg512<<<NN / 4, 256, 0, stream>>>(t2h, offs, csr, dinv, b2, H2h);

  for (int step = 0; step < 3; ++step) {
    // gates partials: 4 K-slices of 256 in one dispatch (grid 128)
    k_mfma_gemm<0><<<4 * (NG / 128) * (2048 / 128), 256, 0, stream>>>(
        qhhi, qhlo, wgh, gp, nullptr, nullptr, nullptr, nullptr,
        NG, 2048, 256, 1024, 1024);
    k_step<<<NG, 256, 0, stream>>>(gp, b_ih, b_hh, cs, H2h, starts, qstar, qhhi, qhlo);
  }
}

// Round 9
// 263.473 us; speedup vs baseline: 1.3157x; 1.2247x over previous
//
#include <hip/hip_runtime.h>
#include <math.h>

#define NN 32768
#define NE 262144
#define NG 256
#define DIN 256
#define DH 512
#define DOUT 512

typedef unsigned short u16;
typedef _Float16 f16;
typedef __attribute__((ext_vector_type(4))) _Float16 f16x4;
typedef __attribute__((ext_vector_type(8))) _Float16 f16x8;
typedef __attribute__((ext_vector_type(4))) float f32x4;

__device__ inline void split2h(float f, f16& h, f16& l) {
  h = (f16)f;
  l = (f16)(f - (float)h);
}

__device__ inline void gload16(const void* g, void* l) {
  __builtin_amdgcn_global_load_lds((const __attribute__((address_space(1))) unsigned int*)g,
                                   (__attribute__((address_space(3))) unsigned int*)l,
                                   16, 0, 0);
}

// ---------------- graph prep ----------------

__global__ void k_count(const int* __restrict__ ei, int* __restrict__ counts) {
  int e = blockIdx.x * 256 + threadIdx.x;
  if (e < NE) atomicAdd(&counts[ei[NE + e]], 1);
}

__global__ __launch_bounds__(128) void k_scanA(const int* __restrict__ counts,
                                               int* __restrict__ bsum) {
  int b = blockIdx.x, t = threadIdx.x;
  int v = counts[b * 128 + t];
  __shared__ int red[128];
  red[t] = v;
  __syncthreads();
#pragma unroll
  for (int o = 64; o > 0; o >>= 1) {
    if (t < o) red[t] += red[t + o];
    __syncthreads();
  }
  if (t == 0) bsum[b] = red[0];
}

__global__ __launch_bounds__(256) void k_scanB(const int* __restrict__ bsum,
                                               int* __restrict__ boff,
                                               int* __restrict__ offs) {
  __shared__ int s[256];
  int t = threadIdx.x;
  int v = bsum[t];
  s[t] = v;
  __syncthreads();
  for (int o = 1; o < 256; o <<= 1) {
    int add = (t >= o) ? s[t - o] : 0;
    __syncthreads();
    s[t] += add;
    __syncthreads();
  }
  boff[t] = s[t] - v;  // exclusive
  if (t == 255) offs[NN] = s[255];
}

__global__ __launch_bounds__(128) void k_scanC(const int* __restrict__ counts,
                                               const int* __restrict__ boff,
                                               int* __restrict__ offs,
                                               float* __restrict__ dinv) {
  int b = blockIdx.x, t = threadIdx.x;
  int v = counts[b * 128 + t];
  __shared__ int s[128];
  s[t] = v;
  __syncthreads();
  for (int o = 1; o < 128; o <<= 1) {
    int add = (t >= o) ? s[t - o] : 0;
    __syncthreads();
    s[t] += add;
    __syncthreads();
  }
  offs[b * 128 + t] = boff[b] + s[t] - v;
  dinv[b * 128 + t] = rsqrtf((float)(v + 1));
}

__global__ void k_fill(const int* __restrict__ ei, const int* __restrict__ offs,
                       int* __restrict__ cursor, int* __restrict__ csr) {
  int e = blockIdx.x * 256 + threadIdx.x;
  if (e < NE) {
    int d = ei[NE + e];
    int pos = offs[d] + atomicAdd(&cursor[d], 1);
    csr[pos] = ei[e];
  }
}

// ---------------- fused prep: x->f16, W1^T, W2^T, combined gates weight, batch starts ----------------
// block sections: [0,8192) half | [8192,8704) W1T | [8704,9728) W2T | [9728,17920) WC | 17920 starts
__global__ void k_prep(const float* __restrict__ x, f16* __restrict__ xh,
                       const float* __restrict__ W1, f16* __restrict__ w1th,
                       const float* __restrict__ W2, f16* __restrict__ w2th,
                       const float* __restrict__ W_ih, const float* __restrict__ W_hh,
                       f16* __restrict__ wgh,
                       const int* __restrict__ batch, int* __restrict__ starts) {
  int b = blockIdx.x;
  if (b < 8192) {  // x -> f16, 4 elems/thread
    int i = (b * 256 + threadIdx.x) << 2;
    float4 v = *(const float4*)(x + i);
    f16x4 h = {(f16)v.x, (f16)v.y, (f16)v.z, (f16)v.w};
    *(f16x4*)(xh + i) = h;
  } else if (b < 8704) {  // W1 [256][512] -> w1th [512][256]
    int idx = (b - 8192) * 256 + threadIdx.x;
    int k = idx >> 9, n = idx & 511;
    w1th[(size_t)n * DIN + k] = (f16)W1[idx];
  } else if (b < 9728) {  // W2 [512][512] -> w2th [512][512]
    int idx = (b - 8704) * 256 + threadIdx.x;
    int k = idx >> 9, n = idx & 511;
    w2th[(size_t)n * DH + k] = (f16)W2[idx];
  } else if (b < 17920) {  // combined gates weight
    int idx = (b - 9728) * 256 + threadIdx.x;
    int n = idx >> 10, c = idx & 1023;
    float v = W_ih[(size_t)n * 1024 + c];
    if (c < 512) v += W_hh[(size_t)n * 512 + c];
    wgh[idx] = (f16)v;
  } else {  // batch starts via binary search
    int g = threadIdx.x;
    int lo = 0, hi = NN;
    while (lo < hi) {
      int mid = (lo + hi) >> 1;
      if (batch[mid] < g) lo = mid + 1; else hi = mid;
    }
    starts[g] = lo;
    if (g == 0) starts[NG] = NN;
  }
}

// ---------------- split-fp16 MFMA GEMM (BK=64 single-buffer, m97 2-barrier structure) ----------------
template <int MODE>
__global__ __launch_bounds__(256) void k_mfma_gemm(
    const f16* __restrict__ Ahi, const f16* __restrict__ Alo,
    const f16* __restrict__ Bhi,
    float* __restrict__ C, f16* __restrict__ Chi, f16* __restrict__ Clo,
    f16* __restrict__ Cf16, const float* __restrict__ bias,
    int M, int N, int K, int lda, int ldb) {
  __shared__ char lds[49152];  // Ahi 16K | Alo 16K | Bhi 16K

  int nbn = N >> 7;
  int nwg = (M >> 7) * nbn;
  int b = blockIdx.x;
  int slice = b / nwg;
  b -= slice * nwg;
  int koff = slice * K;
  int swz = (b & 7) * (nwg >> 3) + (b >> 3);  // nwg % 8 == 0 for all our shapes
  int bn = (swz % nbn) << 7;
  int bm = (swz / nbn) << 7;

  int tid = threadIdx.x;
  int w = tid >> 6, lane = tid & 63;
  int wm = (w >> 1) << 6, wn = (w & 1) << 6;
  int fr = lane & 15;
  int fq = lane >> 4;

  f32x4 acc[4][4];
#pragma unroll
  for (int i = 0; i < 4; ++i)
#pragma unroll
    for (int j = 0; j < 4; ++j) acc[i][j] = (f32x4){0.f, 0.f, 0.f, 0.f};

  for (int ks = 0; ks < K; ks += 64) {
#pragma unroll
    for (int i = 0; i < 4; ++i) {
      int L = i * 256 + tid;
      int row = L >> 3;
      int ke = ((L & 7) ^ (row & 7)) << 3;  // pre-swizzled global source
      int ldsoff = i * 4096 + w * 1024;     // wave-uniform base (+lane*16 by HW)
      gload16(Ahi + (size_t)(bm + row) * lda + koff + ks + ke, lds + ldsoff);
      gload16(Alo + (size_t)(bm + row) * lda + koff + ks + ke, lds + 16384 + ldsoff);
      gload16(Bhi + (size_t)(bn + row) * ldb + koff + ks + ke, lds + 32768 + ldsoff);
    }
    __syncthreads();
#pragma unroll
    for (int kk = 0; kk < 2; ++kk) {
      f16x8 ah[4], al[4], bh[4];
#pragma unroll
      for (int m = 0; m < 4; ++m) {
        int row = wm + m * 16 + fr;
        int boff = row * 128 + (((kk << 6) + (fq << 4)) ^ ((row & 7) << 4));
        ah[m] = *(const f16x8*)(lds + boff);
        al[m] = *(const f16x8*)(lds + 16384 + boff);
      }
#pragma unroll
      for (int n = 0; n < 4; ++n) {
        int row = wn + n * 16 + fr;
        int boff = row * 128 + (((kk << 6) + (fq << 4)) ^ ((row & 7) << 4));
        bh[n] = *(const f16x8*)(lds + 32768 + boff);
      }
#pragma unroll
      for (int m = 0; m < 4; ++m)
#pragma unroll
        for (int n = 0; n < 4; ++n) {
          acc[m][n] = __builtin_amdgcn_mfma_f32_16x16x32_f16(ah[m], bh[n], acc[m][n], 0, 0, 0);
          acc[m][n] = __builtin_amdgcn_mfma_f32_16x16x32_f16(al[m], bh[n], acc[m][n], 0, 0, 0);
        }
    }
    __syncthreads();
  }
#pragma unroll
  for (int m = 0; m < 4; ++m)
#pragma unroll
    for (int n = 0; n < 4; ++n)
#pragma unroll
      for (int i = 0; i < 4; ++i) {
        int r = bm + wm + m * 16 + fq * 4 + i;
        int c = bn + wn + n * 16 + fr;
        float val = acc[m][n][i];
        if (MODE == 1) {
          val += bias[c];
          val = fmaxf(val, 0.f);
          f16 h, l;
          split2h(val, h, l);
          Chi[(size_t)r * N + c] = h;
          Clo[(size_t)r * N + c] = l;
        } else if (MODE == 2) {
          Cf16[(size_t)r * N + c] = (f16)val;
        } else {
          C[(size_t)slice * M * N + (size_t)r * N + c] = val;
        }
      }
}

// ---------------- aggregation, 256-dim fp16 -> f16 hi/lo. One wave per node, ILP-8. ----------------
__global__ __launch_bounds__(256) void k_agg256(const f16* __restrict__ xh,
                                                const int* __restrict__ offs,
                                                const int* __restrict__ csr,
                                                const float* __restrict__ dinv,
                                                f16* __restrict__ ohi, f16* __restrict__ olo) {
  int wv = threadIdx.x >> 6, lane = threadIdx.x & 63;
  int v = blockIdx.x * 4 + wv;
  int f = lane << 2;
  int s = offs[v], t = offs[v + 1];
  float dv = dinv[v];
  f16x4 rs = *(const f16x4*)(xh + (size_t)v * DIN + f);  // self row, issued early
  float a0[4] = {}, a1[4] = {}, a2[4] = {}, a3[4] = {};
  for (int base = s; base < t; base += 64) {
    int rem = min(64, t - base);
    int idx = (lane < rem) ? csr[base + lane] : 0;
    float wl = (lane < rem) ? dinv[idx] : 0.f;
    int i = 0;
    for (; i + 7 < rem; i += 8) {
      int u[8]; float ww[8]; f16x4 r[8];
#pragma unroll
      for (int q = 0; q < 8; ++q) { u[q] = __shfl(idx, i + q); ww[q] = __shfl(wl, i + q); }
#pragma unroll
      for (int q = 0; q < 8; ++q) r[q] = *(const f16x4*)(xh + (size_t)u[q] * DIN + f);
#pragma unroll
      for (int k = 0; k < 4; ++k) {
        a0[k] += ww[0] * (float)r[0][k]; a1[k] += ww[1] * (float)r[1][k];
        a2[k] += ww[2] * (float)r[2][k]; a3[k] += ww[3] * (float)r[3][k];
        a0[k] += ww[4] * (float)r[4][k]; a1[k] += ww[5] * (float)r[5][k];
        a2[k] += ww[6] * (float)r[6][k]; a3[k] += ww[7] * (float)r[7][k];
      }
    }
    for (; i + 1 < rem; i += 2) {
      int u0 = __shfl(idx, i), u1 = __shfl(idx, i + 1);
      float w0 = __shfl(wl, i), w1 = __shfl(wl, i + 1);
      f16x4 r0 = *(const f16x4*)(xh + (size_t)u0 * DIN + f);
      f16x4 r1 = *(const f16x4*)(xh + (size_t)u1 * DIN + f);
#pragma unroll
      for (int k = 0; k < 4; ++k) { a0[k] += w0 * (float)r0[k]; a1[k] += w1 * (float)r1[k]; }
    }
    if (i < rem) {
      int u0 = __shfl(idx, i);
      float w0 = __shfl(wl, i);
      f16x4 r0 = *(const f16x4*)(xh + (size_t)u0 * DIN + f);
#pragma unroll
      for (int k = 0; k < 4; ++k) a0[k] += w0 * (float)r0[k];
    }
  }
  f16x4 vh, vl;
#pragma unroll
  for (int k = 0; k < 4; ++k) {
    float r = (a0[k] + a1[k] + a2[k] + a3[k] + dv * (float)rs[k]) * dv;
    f16 h, l;
    split2h(r, h, l);
    vh[k] = h; vl[k] = l;
  }
  *(f16x4*)(ohi + (size_t)v * DIN + f) = vh;
  *(f16x4*)(olo + (size_t)v * DIN + f) = vl;
}

// ---------------- aggregation, 512-dim fp16 + bias -> fp16. One wave per node, ILP-8. ----------------
__global__ __launch_bounds__(256) void k_agg512(const f16* __restrict__ T2,
                                                const int* __restrict__ offs,
                                                const int* __restrict__ csr,
                                                const float* __restrict__ dinv,
                                                const float* __restrict__ bias,
                                                f16* __restrict__ H2) {
  int wv = threadIdx.x >> 6, lane = threadIdx.x & 63;
  int v = blockIdx.x * 4 + wv;
  int f = lane << 3;
  int s = offs[v], t = offs[v + 1];
  float dv = dinv[v];
  f16x8 rs = *(const f16x8*)(T2 + (size_t)v * DH + f);  // self row, issued early
  float a0[8] = {}, a1[8] = {}, a2[8] = {}, a3[8] = {};
  for (int base = s; base < t; base += 64) {
    int rem = min(64, t - base);
    int idx = (lane < rem) ? csr[base + lane] : 0;
    float wl = (lane < rem) ? dinv[idx] : 0.f;
    int i = 0;
    for (; i + 7 < rem; i += 8) {
      int u[8]; float ww[8]; f16x8 r[8];
#pragma unroll
      for (int q = 0; q < 8; ++q) { u[q] = __shfl(idx, i + q); ww[q] = __shfl(wl, i + q); }
#pragma unroll
      for (int q = 0; q < 8; ++q) r[q] = *(const f16x8*)(T2 + (size_t)u[q] * DH + f);
#pragma unroll
      for (int k = 0; k < 8; ++k) {
        a0[k] += ww[0] * (float)r[0][k]; a1[k] += ww[1] * (float)r[1][k];
        a2[k] += ww[2] * (float)r[2][k]; a3[k] += ww[3] * (float)r[3][k];
        a0[k] += ww[4] * (float)r[4][k]; a1[k] += ww[5] * (float)r[5][k];
        a2[k] += ww[6] * (float)r[6][k]; a3[k] += ww[7] * (float)r[7][k];
      }
    }
    for (; i + 1 < rem; i += 2) {
      int u0 = __shfl(idx, i), u1 = __shfl(idx, i + 1);
      float w0 = __shfl(wl, i), w1 = __shfl(wl, i + 1);
      f16x8 r0 = *(const f16x8*)(T2 + (size_t)u0 * DH + f);
      f16x8 r1 = *(const f16x8*)(T2 + (size_t)u1 * DH + f);
#pragma unroll
      for (int k = 0; k < 8; ++k) { a0[k] += w0 * (float)r0[k]; a1[k] += w1 * (float)r1[k]; }
    }
    if (i < rem) {
      int u0 = __shfl(idx, i);
      float w0 = __shfl(wl, i);
      f16x8 r0 = *(const f16x8*)(T2 + (size_t)u0 * DH + f);
#pragma unroll
      for (int k = 0; k < 8; ++k) a0[k] += w0 * (float)r0[k];
    }
  }
  float4 bb0 = *(const float4*)(bias + f);
  float4 bb1 = *(const float4*)(bias + f + 4);
  float bbv[8] = {bb0.x, bb0.y, bb0.z, bb0.w, bb1.x, bb1.y, bb1.z, bb1.w};
  f16x8 out;
#pragma unroll
  for (int k = 0; k < 8; ++k)
    out[k] = (f16)((a0[k] + a1[k] + a2[k] + a3[k] + dv * (float)rs[k]) * dv + bbv[k]);
  *(f16x8*)(H2 + (size_t)v * DH + f) = out;
}

// ---------------- fused set2set step: LSTM (4 split-K partials) + flash pool. 512 thr / 8 waves. ----------------
__global__ __launch_bounds__(512) void k_step(const float* __restrict__ gp,
                                              const float* __restrict__ b_ih,
                                              const float* __restrict__ b_hh,
                                              float* __restrict__ cs,
                                              const f16* __restrict__ H2,
                                              const int* __restrict__ starts,
                                              float* __restrict__ qstar,
                                              f16* __restrict__ qhhi, f16* __restrict__ qhlo) {
  int g = blockIdx.x;
  int tid = threadIdx.x, wv = tid >> 6, lane = tid & 63;
  __shared__ float shs[512];
  __shared__ float lm[8], lsum[8];
  __shared__ float lr[8][512];

  // --- LSTM phase: thread tid handles gate column j = tid ---
  {
    int j = tid;
    const float* g0 = gp + (size_t)g * 2048;
    float iv = b_ih[j]        + b_hh[j];
    float fv = b_ih[512 + j]  + b_hh[512 + j];
    float gv = b_ih[1024 + j] + b_hh[1024 + j];
    float ov = b_ih[1536 + j] + b_hh[1536 + j];
#pragma unroll
    for (int sl = 0; sl < 4; ++sl) {
      const float* gs = g0 + (size_t)sl * 524288;
      iv += gs[j]; fv += gs[512 + j]; gv += gs[1024 + j]; ov += gs[1536 + j];
    }
    float si = 1.f / (1.f + expf(-iv));
    float sf = 1.f / (1.f + expf(-fv));
    float so = 1.f / (1.f + expf(-ov));
    float c = sf * cs[(size_t)g * 512 + j] + si * tanhf(gv);
    float h = so * tanhf(c);
    cs[(size_t)g * 512 + j] = c;
    shs[j] = h;
    qstar[(size_t)g * 1024 + j] = h;
    f16 hh, hl;
    split2h(h, hh, hl);
    qhhi[(size_t)g * 1024 + j] = hh;
    qhlo[(size_t)g * 1024 + j] = hl;
  }
  __syncthreads();

  // --- pool phase: 8 waves stride the graph's nodes, one-ahead row prefetch ---
  int s = starts[g], t = starts[g + 1];
  int cnt = t - s;
  float hsr[8];
#pragma unroll
  for (int k = 0; k < 8; ++k) hsr[k] = shs[lane * 8 + k];

  float m = -INFINITY, ssum = 0.f;
  float racc[8] = {};
  f16x8 rv = {};
  if (wv < cnt) rv = *(const f16x8*)(H2 + (size_t)(s + wv) * DH + lane * 8);
  for (int i = wv; i < cnt; i += 8) {
    f16x8 cur = rv;
    if (i + 8 < cnt) rv = *(const f16x8*)(H2 + (size_t)(s + i + 8) * DH + lane * 8);
    float e = 0.f;
#pragma unroll
    for (int k = 0; k < 8; ++k) e += (float)cur[k] * hsr[k];
#pragma unroll
    for (int o = 1; o < 64; o <<= 1) e += __shfl_xor(e, o);
    float mn = fmaxf(m, e);
    float scale = expf(m - mn);   // first iter: exp(-inf)=0
    float p = expf(e - mn);
    ssum = ssum * scale + p;
#pragma unroll
    for (int k = 0; k < 8; ++k) racc[k] = racc[k] * scale + p * (float)cur[k];
    m = mn;
  }
  if (lane == 0) { lm[wv] = m; lsum[wv] = ssum; }
#pragma unroll
  for (int k = 0; k < 8; ++k) lr[wv][lane * 8 + k] = racc[k];
  __syncthreads();
  float M = -INFINITY;
#pragma unroll
  for (int w2 = 0; w2 < 8; ++w2) M = fmaxf(M, lm[w2]);
  if (!(M > -3.0e38f)) M = 0.f;  // empty graph
  float denom = 0.f;
  float sc[8];
#pragma unroll
  for (int w2 = 0; w2 < 8; ++w2) { sc[w2] = expf(lm[w2] - M); denom += lsum[w2] * sc[w2]; }
  float inv = 1.f / fmaxf(denom, 1e-12f);
  int f = tid;  // 0..511
  float r = 0.f;
#pragma unroll
  for (int w2 = 0; w2 < 8; ++w2) r += lr[w2][f] * sc[w2];
  r *= inv;
  qstar[(size_t)g * 1024 + 512 + f] = r;
  f16 h0, l0;
  split2h(r, h0, l0);
  qhhi[(size_t)g * 1024 + 512 + f] = h0;
  qhlo[(size_t)g * 1024 + 512 + f] = l0;
}

// ---------------- launch ----------------
extern "C" void kernel_launch(void* const* d_in, const int* in_sizes, int n_in,
                              void* d_out, int out_size, void* d_ws, size_t ws_size,
                              hipStream_t stream) {
  const float* x     = (const float*)d_in[0];
  const int*   ei    = (const int*)d_in[1];
  const int*   batch = (const int*)d_in[2];
  const float* W1    = (const float*)d_in[3];
  const float* b1    = (const float*)d_in[4];
  const float* W2    = (const float*)d_in[5];
  const float* b2    = (const float*)d_in[6];
  const float* W_ih  = (const float*)d_in[7];
  const float* W_hh  = (const float*)d_in[8];
  const float* b_ih  = (const float*)d_in[9];
  const float* b_hh  = (const float*)d_in[10];
  float* qstar = (float*)d_out;

  char* w = (char*)d_ws;
  size_t off = 0;
  auto carve = [&](size_t bytes) -> void* {
    void* p = w + off;
    off += (bytes + 255) & ~(size_t)255;
    return p;
  };
  f16* xh      = (f16*)carve((size_t)NN * DIN * 2);
  f16* axhi    = (f16*)carve((size_t)NN * DIN * 2);
  f16* axlo    = (f16*)carve((size_t)NN * DIN * 2);
  f16* h1hi    = (f16*)carve((size_t)NN * DH * 2);
  f16* h1lo    = (f16*)carve((size_t)NN * DH * 2);
  f16* t2h     = (f16*)carve((size_t)NN * DH * 2);
  f16* H2h     = (f16*)carve((size_t)NN * DH * 2);
  f16* w1th    = (f16*)carve((size_t)DH * DIN * 2);
  f16* w2th    = (f16*)carve((size_t)DH * DH * 2);
  f16* wgh     = (f16*)carve((size_t)2048 * 1024 * 2);
  float* gp    = (float*)carve((size_t)4 * NG * 2048 * 4);
  // zero-group A: counts + cursor (contiguous, 256B-aligned sizes)
  int* counts  = (int*)carve((size_t)NN * 4);
  int* cursor  = (int*)carve((size_t)NN * 4);
  // zero-group B: cs + qhhi + qhlo (contiguous; each size divisible by 256)
  float* cs    = (float*)carve((size_t)NG * DOUT * 4);
  f16* qhhi    = (f16*)carve((size_t)NG * 1024 * 2);
  f16* qhlo    = (f16*)carve((size_t)NG * 1024 * 2);
  int* offs    = (int*)carve((size_t)(NN + 1) * 4);
  int* csr     = (int*)carve((size_t)NE * 4);
  float* dinv  = (float*)carve((size_t)NN * 4);
  int* starts  = (int*)carve((size_t)(NG + 1) * 4);
  int* bsum    = (int*)carve((size_t)256 * 4);
  int* boff    = (int*)carve((size_t)256 * 4);

  hipMemsetAsync(counts, 0, (size_t)2 * NN * 4, stream);                       // counts+cursor
  hipMemsetAsync(cs, 0, (size_t)NG * DOUT * 4 + (size_t)2 * NG * 1024 * 2, stream);  // cs+qhhi+qhlo

  k_prep<<<17921, 256, 0, stream>>>(x, xh, W1, w1th, W2, w2th, W_ih, W_hh, wgh, batch, starts);
  k_count<<<NE / 256, 256, 0, stream>>>(ei, counts);
  k_scanA<<<NN / 128, 128, 0, stream>>>(counts, bsum);
  k_scanB<<<1, 256, 0, stream>>>(bsum, boff, offs);
  k_scanC<<<NN / 128, 128, 0, stream>>>(counts, boff, offs, dinv);
  k_fill<<<NE / 256, 256, 0, stream>>>(ei, offs, cursor, csr);

  // layer 1: aggx = Agg(x) ; H1 = relu(aggx@W1 + b1)
  k_agg256<<<NN / 4, 256, 0, stream>>>(xh, offs, csr, dinv, axhi, axlo);
  k_mfma_gemm<1><<<(NN / 128) * (DH / 128), 256, 0, stream>>>(
      axhi, axlo, w1th, nullptr, h1hi, h1lo, nullptr, b1, NN, DH, DIN, DIN, DIN);
  // layer 2: t2 = H1@W2 ; H2 = Agg(t2) + b2
  k_mfma_gemm<2><<<(NN / 128) * (DH / 128), 256, 0, stream>>>(
      h1hi, h1lo, w2th, nullptr, nullptr, nullptr, t2h, nullptr, NN, DH, DH, DH, DH);
  k_agg512<<<NN / 4, 256, 0, stream>>>(t2h, offs, csr, dinv, b2, H2h);

  for (int step = 0; step < 3; ++step) {
    // gates partials: 4 K-slices of 256 in one dispatch (grid 128)
    k_mfma_gemm<0><<<4 * (NG / 128) * (2048 / 128), 256, 0, stream>>>(
        qhhi, qhlo, wgh, gp, nullptr, nullptr, nullptr, nullptr,
        NG, 2048, 256, 1024, 1024);
    k_step<<<NG, 512, 0, stream>>>(gp, b_ih, b_hh, cs, H2h, starts, qstar, qhhi, qhlo);
  }
}

// Round 10
// 247.738 us; speedup vs baseline: 1.3993x; 1.0635x over previous
//
#include <hip/hip_runtime.h>
#include <math.h>

#define NN 32768
#define NE 262144
#define NG 256
#define DIN 256
#define DH 512
#define DOUT 512

typedef unsigned short u16;
typedef _Float16 f16;
typedef __attribute__((ext_vector_type(4))) _Float16 f16x4;
typedef __attribute__((ext_vector_type(8))) _Float16 f16x8;
typedef __attribute__((ext_vector_type(4))) float f32x4;

__device__ inline void split2h(float f, f16& h, f16& l) {
  h = (f16)f;
  l = (f16)(f - (float)h);
}

__device__ inline void gload16(const void* g, void* l) {
  __builtin_amdgcn_global_load_lds((const __attribute__((address_space(1))) unsigned int*)g,
                                   (__attribute__((address_space(3))) unsigned int*)l,
                                   16, 0, 0);
}

// ---------------- graph prep ----------------

__global__ void k_count(const int* __restrict__ ei, int* __restrict__ counts) {
  int e = blockIdx.x * 256 + threadIdx.x;
  if (e < NE) atomicAdd(&counts[ei[NE + e]], 1);
}

__global__ __launch_bounds__(128) void k_scanA(const int* __restrict__ counts,
                                               int* __restrict__ bsum) {
  int b = blockIdx.x, t = threadIdx.x;
  int v = counts[b * 128 + t];
  __shared__ int red[128];
  red[t] = v;
  __syncthreads();
#pragma unroll
  for (int o = 64; o > 0; o >>= 1) {
    if (t < o) red[t] += red[t + o];
    __syncthreads();
  }
  if (t == 0) bsum[b] = red[0];
}

__global__ __launch_bounds__(256) void k_scanB(const int* __restrict__ bsum,
                                               int* __restrict__ boff,
                                               int* __restrict__ offs) {
  __shared__ int s[256];
  int t = threadIdx.x;
  int v = bsum[t];
  s[t] = v;
  __syncthreads();
  for (int o = 1; o < 256; o <<= 1) {
    int add = (t >= o) ? s[t - o] : 0;
    __syncthreads();
    s[t] += add;
    __syncthreads();
  }
  boff[t] = s[t] - v;  // exclusive
  if (t == 255) offs[NN] = s[255];
}

__global__ __launch_bounds__(128) void k_scanC(const int* __restrict__ counts,
                                               const int* __restrict__ boff,
                                               int* __restrict__ offs,
                                               float* __restrict__ dinv) {
  int b = blockIdx.x, t = threadIdx.x;
  int v = counts[b * 128 + t];
  __shared__ int s[128];
  s[t] = v;
  __syncthreads();
  for (int o = 1; o < 128; o <<= 1) {
    int add = (t >= o) ? s[t - o] : 0;
    __syncthreads();
    s[t] += add;
    __syncthreads();
  }
  offs[b * 128 + t] = boff[b] + s[t] - v;
  dinv[b * 128 + t] = rsqrtf((float)(v + 1));
}

__global__ void k_fill(const int* __restrict__ ei, const int* __restrict__ offs,
                       int* __restrict__ cursor, int* __restrict__ csr) {
  int e = blockIdx.x * 256 + threadIdx.x;
  if (e < NE) {
    int d = ei[NE + e];
    int pos = offs[d] + atomicAdd(&cursor[d], 1);
    csr[pos] = ei[e];
  }
}

// ---------------- fused prep: x->f16, W1^T, W2^T, combined gates weight, batch starts ----------------
__global__ void k_prep(const float* __restrict__ x, f16* __restrict__ xh,
                       const float* __restrict__ W1, f16* __restrict__ w1th,
                       const float* __restrict__ W2, f16* __restrict__ w2th,
                       const float* __restrict__ W_ih, const float* __restrict__ W_hh,
                       f16* __restrict__ wgh,
                       const int* __restrict__ batch, int* __restrict__ starts) {
  int b = blockIdx.x;
  if (b < 8192) {  // x -> f16, 4 elems/thread
    int i = (b * 256 + threadIdx.x) << 2;
    float4 v = *(const float4*)(x + i);
    f16x4 h = {(f16)v.x, (f16)v.y, (f16)v.z, (f16)v.w};
    *(f16x4*)(xh + i) = h;
  } else if (b < 8704) {  // W1 [256][512] -> w1th [512][256]
    int idx = (b - 8192) * 256 + threadIdx.x;
    int k = idx >> 9, n = idx & 511;
    w1th[(size_t)n * DIN + k] = (f16)W1[idx];
  } else if (b < 9728) {  // W2 [512][512] -> w2th [512][512]
    int idx = (b - 8704) * 256 + threadIdx.x;
    int k = idx >> 9, n = idx & 511;
    w2th[(size_t)n * DH + k] = (f16)W2[idx];
  } else if (b < 17920) {  // combined gates weight
    int idx = (b - 9728) * 256 + threadIdx.x;
    int n = idx >> 10, c = idx & 1023;
    float v = W_ih[(size_t)n * 1024 + c];
    if (c < 512) v += W_hh[(size_t)n * 512 + c];
    wgh[idx] = (f16)v;
  } else {  // batch starts via binary search
    int g = threadIdx.x;
    int lo = 0, hi = NN;
    while (lo < hi) {
      int mid = (lo + hi) >> 1;
      if (batch[mid] < g) lo = mid + 1; else hi = mid;
    }
    starts[g] = lo;
    if (g == 0) starts[NG] = NN;
  }
}

// ---------------- fp16 MFMA GEMM (BK=64 single-buffer, m97 2-barrier structure) ----------------
// TERMS=1: C = A@B^T, pure fp16 operands (LDS 32K, A|B).
// TERMS=2: C = (Ahi+Alo)@B^T (LDS 48K, Ahi|Alo|B).
// MODE 0: fp32 C partial at slice*M*N. MODE 1: +bias, relu, f16 out. MODE 2: f16 out.
template <int MODE, int TERMS>
__global__ __launch_bounds__(256) void k_mfma_gemm(
    const f16* __restrict__ Ahi, const f16* __restrict__ Alo,
    const f16* __restrict__ Bhi,
    float* __restrict__ C, f16* __restrict__ Cf16, const float* __restrict__ bias,
    int M, int N, int K, int lda, int ldb) {
  constexpr int BOFF = (TERMS == 2) ? 32768 : 16384;
  __shared__ char lds[(TERMS == 2) ? 49152 : 32768];

  int nbn = N >> 7;
  int nwg = (M >> 7) * nbn;
  int b = blockIdx.x;
  int slice = b / nwg;
  b -= slice * nwg;
  int koff = slice * K;
  int swz = (b & 7) * (nwg >> 3) + (b >> 3);  // nwg % 8 == 0 for all our shapes
  int bn = (swz % nbn) << 7;
  int bm = (swz / nbn) << 7;

  int tid = threadIdx.x;
  int w = tid >> 6, lane = tid & 63;
  int wm = (w >> 1) << 6, wn = (w & 1) << 6;
  int fr = lane & 15;
  int fq = lane >> 4;

  f32x4 acc[4][4];
#pragma unroll
  for (int i = 0; i < 4; ++i)
#pragma unroll
    for (int j = 0; j < 4; ++j) acc[i][j] = (f32x4){0.f, 0.f, 0.f, 0.f};

  for (int ks = 0; ks < K; ks += 64) {
#pragma unroll
    for (int i = 0; i < 4; ++i) {
      int L = i * 256 + tid;
      int row = L >> 3;
      int ke = ((L & 7) ^ (row & 7)) << 3;  // pre-swizzled global source
      int ldsoff = i * 4096 + w * 1024;     // wave-uniform base (+lane*16 by HW)
      gload16(Ahi + (size_t)(bm + row) * lda + koff + ks + ke, lds + ldsoff);
      if (TERMS == 2)
        gload16(Alo + (size_t)(bm + row) * lda + koff + ks + ke, lds + 16384 + ldsoff);
      gload16(Bhi + (size_t)(bn + row) * ldb + koff + ks + ke, lds + BOFF + ldsoff);
    }
    __syncthreads();
#pragma unroll
    for (int kk = 0; kk < 2; ++kk) {
      f16x8 ah[4], al[4], bh[4];
#pragma unroll
      for (int m = 0; m < 4; ++m) {
        int row = wm + m * 16 + fr;
        int boff = row * 128 + (((kk << 6) + (fq << 4)) ^ ((row & 7) << 4));
        ah[m] = *(const f16x8*)(lds + boff);
        if (TERMS == 2) al[m] = *(const f16x8*)(lds + 16384 + boff);
      }
#pragma unroll
      for (int n = 0; n < 4; ++n) {
        int row = wn + n * 16 + fr;
        int boff = row * 128 + (((kk << 6) + (fq << 4)) ^ ((row & 7) << 4));
        bh[n] = *(const f16x8*)(lds + BOFF + boff);
      }
#pragma unroll
      for (int m = 0; m < 4; ++m)
#pragma unroll
        for (int n = 0; n < 4; ++n) {
          acc[m][n] = __builtin_amdgcn_mfma_f32_16x16x32_f16(ah[m], bh[n], acc[m][n], 0, 0, 0);
          if (TERMS == 2)
            acc[m][n] = __builtin_amdgcn_mfma_f32_16x16x32_f16(al[m], bh[n], acc[m][n], 0, 0, 0);
        }
    }
    __syncthreads();
  }
#pragma unroll
  for (int m = 0; m < 4; ++m)
#pragma unroll
    for (int n = 0; n < 4; ++n)
#pragma unroll
      for (int i = 0; i < 4; ++i) {
        int r = bm + wm + m * 16 + fq * 4 + i;
        int c = bn + wn + n * 16 + fr;
        float val = acc[m][n][i];
        if (MODE == 1) {
          val += bias[c];
          val = fmaxf(val, 0.f);
          Cf16[(size_t)r * N + c] = (f16)val;
        } else if (MODE == 2) {
          Cf16[(size_t)r * N + c] = (f16)val;
        } else {
          C[(size_t)slice * M * N + (size_t)r * N + c] = val;
        }
      }
}

// ---------------- aggregation, 256-dim fp16 -> fp16. One wave per node, ILP-8. ----------------
__global__ __launch_bounds__(256) void k_agg256(const f16* __restrict__ xh,
                                                const int* __restrict__ offs,
                                                const int* __restrict__ csr,
                                                const float* __restrict__ dinv,
                                                f16* __restrict__ oh) {
  int wv = threadIdx.x >> 6, lane = threadIdx.x & 63;
  int v = blockIdx.x * 4 + wv;
  int f = lane << 2;
  int s = offs[v], t = offs[v + 1];
  float dv = dinv[v];
  f16x4 rs = *(const f16x4*)(xh + (size_t)v * DIN + f);  // self row, issued early
  float a0[4] = {}, a1[4] = {}, a2[4] = {}, a3[4] = {};
  for (int base = s; base < t; base += 64) {
    int rem = min(64, t - base);
    int idx = (lane < rem) ? csr[base + lane] : 0;
    float wl = (lane < rem) ? dinv[idx] : 0.f;
    int i = 0;
    for (; i + 7 < rem; i += 8) {
      int u[8]; float ww[8]; f16x4 r[8];
#pragma unroll
      for (int q = 0; q < 8; ++q) { u[q] = __shfl(idx, i + q); ww[q] = __shfl(wl, i + q); }
#pragma unroll
      for (int q = 0; q < 8; ++q) r[q] = *(const f16x4*)(xh + (size_t)u[q] * DIN + f);
#pragma unroll
      for (int k = 0; k < 4; ++k) {
        a0[k] += ww[0] * (float)r[0][k]; a1[k] += ww[1] * (float)r[1][k];
        a2[k] += ww[2] * (float)r[2][k]; a3[k] += ww[3] * (float)r[3][k];
        a0[k] += ww[4] * (float)r[4][k]; a1[k] += ww[5] * (float)r[5][k];
        a2[k] += ww[6] * (float)r[6][k]; a3[k] += ww[7] * (float)r[7][k];
      }
    }
    for (; i + 1 < rem; i += 2) {
      int u0 = __shfl(idx, i), u1 = __shfl(idx, i + 1);
      float w0 = __shfl(wl, i), w1 = __shfl(wl, i + 1);
      f16x4 r0 = *(const f16x4*)(xh + (size_t)u0 * DIN + f);
      f16x4 r1 = *(const f16x4*)(xh + (size_t)u1 * DIN + f);
#pragma unroll
      for (int k = 0; k < 4; ++k) { a0[k] += w0 * (float)r0[k]; a1[k] += w1 * (float)r1[k]; }
    }
    if (i < rem) {
      int u0 = __shfl(idx, i);
      float w0 = __shfl(wl, i);
      f16x4 r0 = *(const f16x4*)(xh + (size_t)u0 * DIN + f);
#pragma unroll
      for (int k = 0; k < 4; ++k) a0[k] += w0 * (float)r0[k];
    }
  }
  f16x4 vh;
#pragma unroll
  for (int k = 0; k < 4; ++k)
    vh[k] = (f16)((a0[k] + a1[k] + a2[k] + a3[k] + dv * (float)rs[k]) * dv);
  *(f16x4*)(oh + (size_t)v * DIN + f) = vh;
}

// ---------------- aggregation, 512-dim, COLUMN-HALF pass (256 cols), fp16+bias -> fp16 ----------------
// Two sequential launches (colbase 0, 256) shrink the randomly-gathered working set 32->16 MB
// so per-XCD L2 (4 MB) captures more reuse. One wave per node, f16x4 (8B/lane), ILP-8.
__global__ __launch_bounds__(256) void k_agg512(const f16* __restrict__ T2,
                                                const int* __restrict__ offs,
                                                const int* __restrict__ csr,
                                                const float* __restrict__ dinv,
                                                const float* __restrict__ bias,
                                                f16* __restrict__ H2, int colbase) {
  int wv = threadIdx.x >> 6, lane = threadIdx.x & 63;
  int v = blockIdx.x * 4 + wv;
  int f = colbase + (lane << 2);
  int s = offs[v], t = offs[v + 1];
  float dv = dinv[v];
  f16x4 rs = *(const f16x4*)(T2 + (size_t)v * DH + f);  // self row, issued early
  float a0[4] = {}, a1[4] = {}, a2[4] = {}, a3[4] = {};
  for (int base = s; base < t; base += 64) {
    int rem = min(64, t - base);
    int idx = (lane < rem) ? csr[base + lane] : 0;
    float wl = (lane < rem) ? dinv[idx] : 0.f;
    int i = 0;
    for (; i + 7 < rem; i += 8) {
      int u[8]; float ww[8]; f16x4 r[8];
#pragma unroll
      for (int q = 0; q < 8; ++q) { u[q] = __shfl(idx, i + q); ww[q] = __shfl(wl, i + q); }
#pragma unroll
      for (int q = 0; q < 8; ++q) r[q] = *(const f16x4*)(T2 + (size_t)u[q] * DH + f);
#pragma unroll
      for (int k = 0; k < 4; ++k) {
        a0[k] += ww[0] * (float)r[0][k]; a1[k] += ww[1] * (float)r[1][k];
        a2[k] += ww[2] * (float)r[2][k]; a3[k] += ww[3] * (float)r[3][k];
        a0[k] += ww[4] * (float)r[4][k]; a1[k] += ww[5] * (float)r[5][k];
        a2[k] += ww[6] * (float)r[6][k]; a3[k] += ww[7] * (float)r[7][k];
      }
    }
    for (; i + 1 < rem; i += 2) {
      int u0 = __shfl(idx, i), u1 = __shfl(idx, i + 1);
      float w0 = __shfl(wl, i), w1 = __shfl(wl, i + 1);
      f16x4 r0 = *(const f16x4*)(T2 + (size_t)u0 * DH + f);
      f16x4 r1 = *(const f16x4*)(T2 + (size_t)u1 * DH + f);
#pragma unroll
      for (int k = 0; k < 4; ++k) { a0[k] += w0 * (float)r0[k]; a1[k] += w1 * (float)r1[k]; }
    }
    if (i < rem) {
      int u0 = __shfl(idx, i);
      float w0 = __shfl(wl, i);
      f16x4 r0 = *(const f16x4*)(T2 + (size_t)u0 * DH + f);
#pragma unroll
      for (int k = 0; k < 4; ++k) a0[k] += w0 * (float)r0[k];
    }
  }
  float4 bb = *(const float4*)(bias + f);
  float bbv[4] = {bb.x, bb.y, bb.z, bb.w};
  f16x4 out;
#pragma unroll
  for (int k = 0; k < 4; ++k)
    out[k] = (f16)((a0[k] + a1[k] + a2[k] + a3[k] + dv * (float)rs[k]) * dv + bbv[k]);
  *(f16x4*)(H2 + (size_t)v * DH + f) = out;
}

// ---------------- fused set2set step: LSTM (8 split-K partials) + flash pool. 512 thr / 8 waves. ----------------
__global__ __launch_bounds__(512) void k_step(const float* __restrict__ gp,
                                              const float* __restrict__ b_ih,
                                              const float* __restrict__ b_hh,
                                              float* __restrict__ cs,
                                              const f16* __restrict__ H2,
                                              const int* __restrict__ starts,
                                              float* __restrict__ qstar,
                                              f16* __restrict__ qhhi, f16* __restrict__ qhlo) {
  int g = blockIdx.x;
  int tid = threadIdx.x, wv = tid >> 6, lane = tid & 63;
  __shared__ float shs[512];
  __shared__ float lm[8], lsum[8];
  __shared__ float lr[8][512];

  // --- LSTM phase ---
  {
    int j = tid;
    const float* g0 = gp + (size_t)g * 2048;
    float iv = b_ih[j]        + b_hh[j];
    float fv = b_ih[512 + j]  + b_hh[512 + j];
    float gv = b_ih[1024 + j] + b_hh[1024 + j];
    float ov = b_ih[1536 + j] + b_hh[1536 + j];
#pragma unroll
    for (int sl = 0; sl < 8; ++sl) {
      const float* gs = g0 + (size_t)sl * 524288;
      iv += gs[j]; fv += gs[512 + j]; gv += gs[1024 + j]; ov += gs[1536 + j];
    }
    float si = 1.f / (1.f + expf(-iv));
    float sf = 1.f / (1.f + expf(-fv));
    float so = 1.f / (1.f + expf(-ov));
    float c = sf * cs[(size_t)g * 512 + j] + si * tanhf(gv);
    float h = so * tanhf(c);
    cs[(size_t)g * 512 + j] = c;
    shs[j] = h;
    qstar[(size_t)g * 1024 + j] = h;
    f16 hh, hl;
    split2h(h, hh, hl);
    qhhi[(size_t)g * 1024 + j] = hh;
    qhlo[(size_t)g * 1024 + j] = hl;
  }
  __syncthreads();

  // --- pool phase: 8 waves stride the graph's nodes, one-ahead row prefetch ---
  int s = starts[g], t = starts[g + 1];
  int cnt = t - s;
  float hsr[8];
#pragma unroll
  for (int k = 0; k < 8; ++k) hsr[k] = shs[lane * 8 + k];

  float m = -INFINITY, ssum = 0.f;
  float racc[8] = {};
  f16x8 rv = {};
  if (wv < cnt) rv = *(const f16x8*)(H2 + (size_t)(s + wv) * DH + lane * 8);
  for (int i = wv; i < cnt; i += 8) {
    f16x8 cur = rv;
    if (i + 8 < cnt) rv = *(const f16x8*)(H2 + (size_t)(s + i + 8) * DH + lane * 8);
    float e = 0.f;
#pragma unroll
    for (int k = 0; k < 8; ++k) e += (float)cur[k] * hsr[k];
#pragma unroll
    for (int o = 1; o < 64; o <<= 1) e += __shfl_xor(e, o);
    float mn = fmaxf(m, e);
    float scale = expf(m - mn);   // first iter: exp(-inf)=0
    float p = expf(e - mn);
    ssum = ssum * scale + p;
#pragma unroll
    for (int k = 0; k < 8; ++k) racc[k] = racc[k] * scale + p * (float)cur[k];
    m = mn;
  }
  if (lane == 0) { lm[wv] = m; lsum[wv] = ssum; }
#pragma unroll
  for (int k = 0; k < 8; ++k) lr[wv][lane * 8 + k] = racc[k];
  __syncthreads();
  float M = -INFINITY;
#pragma unroll
  for (int w2 = 0; w2 < 8; ++w2) M = fmaxf(M, lm[w2]);
  if (!(M > -3.0e38f)) M = 0.f;  // empty graph
  float denom = 0.f;
  float sc[8];
#pragma unroll
  for (int w2 = 0; w2 < 8; ++w2) { sc[w2] = expf(lm[w2] - M); denom += lsum[w2] * sc[w2]; }
  float inv = 1.f / fmaxf(denom, 1e-12f);
  int f = tid;  // 0..511
  float r = 0.f;
#pragma unroll
  for (int w2 = 0; w2 < 8; ++w2) r += lr[w2][f] * sc[w2];
  r *= inv;
  qstar[(size_t)g * 1024 + 512 + f] = r;
  f16 h0, l0;
  split2h(r, h0, l0);
  qhhi[(size_t)g * 1024 + 512 + f] = h0;
  qhlo[(size_t)g * 1024 + 512 + f] = l0;
}

// ---------------- launch ----------------
extern "C" void kernel_launch(void* const* d_in, const int* in_sizes, int n_in,
                              void* d_out, int out_size, void* d_ws, size_t ws_size,
                              hipStream_t stream) {
  const float* x     = (const float*)d_in[0];
  const int*   ei    = (const int*)d_in[1];
  const int*   batch = (const int*)d_in[2];
  const float* W1    = (const float*)d_in[3];
  const float* b1    = (const float*)d_in[4];
  const float* W2    = (const float*)d_in[5];
  const float* b2    = (const float*)d_in[6];
  const float* W_ih  = (const float*)d_in[7];
  const float* W_hh  = (const float*)d_in[8];
  const float* b_ih  = (const float*)d_in[9];
  const float* b_hh  = (const float*)d_in[10];
  float* qstar = (float*)d_out;

  char* w = (char*)d_ws;
  size_t off = 0;
  auto carve = [&](size_t bytes) -> void* {
    void* p = w + off;
    off += (bytes + 255) & ~(size_t)255;
    return p;
  };
  f16* xh      = (f16*)carve((size_t)NN * DIN * 2);
  f16* axh     = (f16*)carve((size_t)NN * DIN * 2);
  f16* h1h     = (f16*)carve((size_t)NN * DH * 2);
  f16* t2h     = (f16*)carve((size_t)NN * DH * 2);
  f16* H2h     = (f16*)carve((size_t)NN * DH * 2);
  f16* w1th    = (f16*)carve((size_t)DH * DIN * 2);
  f16* w2th    = (f16*)carve((size_t)DH * DH * 2);
  f16* wgh     = (f16*)carve((size_t)2048 * 1024 * 2);
  float* gp    = (float*)carve((size_t)8 * NG * 2048 * 4);
  // zero-group A: counts + cursor (contiguous)
  int* counts  = (int*)carve((size_t)NN * 4);
  int* cursor  = (int*)carve((size_t)NN * 4);
  // zero-group B: cs + qhhi + qhlo (contiguous)
  float* cs    = (float*)carve((size_t)NG * DOUT * 4);
  f16* qhhi    = (f16*)carve((size_t)NG * 1024 * 2);
  f16* qhlo    = (f16*)carve((size_t)NG * 1024 * 2);
  int* offs    = (int*)carve((size_t)(NN + 1) * 4);
  int* csr     = (int*)carve((size_t)NE * 4);
  float* dinv  = (float*)carve((size_t)NN * 4);
  int* starts  = (int*)carve((size_t)(NG + 1) * 4);
  int* bsum    = (int*)carve((size_t)256 * 4);
  int* boff    = (int*)carve((size_t)256 * 4);

  hipMemsetAsync(counts, 0, (size_t)2 * NN * 4, stream);
  hipMemsetAsync(cs, 0, (size_t)NG * DOUT * 4 + (size_t)2 * NG * 1024 * 2, stream);

  k_prep<<<17921, 256, 0, stream>>>(x, xh, W1, w1th, W2, w2th, W_ih, W_hh, wgh, batch, starts);
  k_count<<<NE / 256, 256, 0, stream>>>(ei, counts);
  k_scanA<<<NN / 128, 128, 0, stream>>>(counts, bsum);
  k_scanB<<<1, 256, 0, stream>>>(bsum, boff, offs);
  k_scanC<<<NN / 128, 128, 0, stream>>>(counts, boff, offs, dinv);
  k_fill<<<NE / 256, 256, 0, stream>>>(ei, offs, cursor, csr);

  // layer 1: aggx = Agg(x) ; H1 = relu(aggx@W1 + b1)   [pure fp16 GEMM]
  k_agg256<<<NN / 4, 256, 0, stream>>>(xh, offs, csr, dinv, axh);
  k_mfma_gemm<1, 1><<<(NN / 128) * (DH / 128), 256, 0, stream>>>(
      axh, nullptr, w1th, nullptr, h1h, b1, NN, DH, DIN, DIN, DIN);
  // layer 2: t2 = H1@W2 ; H2 = Agg(t2) + b2            [pure fp16 GEMM, column-split agg]
  k_mfma_gemm<2, 1><<<(NN / 128) * (DH / 128), 256, 0, stream>>>(
      h1h, nullptr, w2th, nullptr, t2h, nullptr, NN, DH, DH, DH, DH);
  k_agg512<<<NN / 4, 256, 0, stream>>>(t2h, offs, csr, dinv, b2, H2h, 0);
  k_agg512<<<NN / 4, 256, 0, stream>>>(t2h, offs, csr, dinv, b2, H2h, 256);

  for (int step = 0; step < 3; ++step) {
    // gates partials: 8 K-slices of 128 in one dispatch (grid 256) [2-term split fp16]
    k_mfma_gemm<0, 2><<<8 * (NG / 128) * (2048 / 128), 256, 0, stream>>>(
        qhhi, qhlo, wgh, gp, nullptr, nullptr, NG, 2048, 128, 1024, 1024);
    k_step<<<NG, 512, 0, stream>>>(gp, b_ih, b_hh, cs, H2h, starts, qstar, qhhi, qhlo);
  }
}

// Round 11
// 223.687 us; speedup vs baseline: 1.5497x; 1.1075x over previous
//
#include <hip/hip_runtime.h>
#include <math.h>

#define NN 32768
#define NE 262144
#define NG 256
#define DIN 256
#define DH 512
#define DOUT 512

typedef unsigned short u16;
typedef _Float16 f16;
typedef __attribute__((ext_vector_type(4))) _Float16 f16x4;
typedef __attribute__((ext_vector_type(8))) _Float16 f16x8;
typedef __attribute__((ext_vector_type(4))) float f32x4;

__device__ inline void split2h(float f, f16& h, f16& l) {
  h = (f16)f;
  l = (f16)(f - (float)h);
}

__device__ inline void gload16(const void* g, void* l) {
  __builtin_amdgcn_global_load_lds((const __attribute__((address_space(1))) unsigned int*)g,
                                   (__attribute__((address_space(3))) unsigned int*)l,
                                   16, 0, 0);
}

// ---------------- graph prep ----------------

__global__ __launch_bounds__(128) void k_scanA(const int* __restrict__ counts,
                                               int* __restrict__ bsum) {
  int b = blockIdx.x, t = threadIdx.x;
  int v = counts[b * 128 + t];
  __shared__ int red[128];
  red[t] = v;
  __syncthreads();
#pragma unroll
  for (int o = 64; o > 0; o >>= 1) {
    if (t < o) red[t] += red[t + o];
    __syncthreads();
  }
  if (t == 0) bsum[b] = red[0];
}

__global__ __launch_bounds__(256) void k_scanB(const int* __restrict__ bsum,
                                               int* __restrict__ boff,
                                               int* __restrict__ offs) {
  __shared__ int s[256];
  int t = threadIdx.x;
  int v = bsum[t];
  s[t] = v;
  __syncthreads();
  for (int o = 1; o < 256; o <<= 1) {
    int add = (t >= o) ? s[t - o] : 0;
    __syncthreads();
    s[t] += add;
    __syncthreads();
  }
  boff[t] = s[t] - v;  // exclusive
  if (t == 255) offs[NN] = s[255];
}

__global__ __launch_bounds__(128) void k_scanC(const int* __restrict__ counts,
                                               const int* __restrict__ boff,
                                               int* __restrict__ offs,
                                               float* __restrict__ dinv) {
  int b = blockIdx.x, t = threadIdx.x;
  int v = counts[b * 128 + t];
  __shared__ int s[128];
  s[t] = v;
  __syncthreads();
  for (int o = 1; o < 128; o <<= 1) {
    int add = (t >= o) ? s[t - o] : 0;
    __syncthreads();
    s[t] += add;
    __syncthreads();
  }
  offs[b * 128 + t] = boff[b] + s[t] - v;
  dinv[b * 128 + t] = rsqrtf((float)(v + 1));
}

__global__ void k_fill(const int* __restrict__ ei, const int* __restrict__ offs,
                       int* __restrict__ cursor, int* __restrict__ csr) {
  int e = blockIdx.x * 256 + threadIdx.x;
  if (e < NE) {
    int d = ei[NE + e];
    int pos = offs[d] + atomicAdd(&cursor[d], 1);
    csr[pos] = ei[e];
  }
}

// ---------------- fused prep: x->f16, W1^T, W2^T, gates weight, starts, edge count ----------------
__global__ void k_prep(const float* __restrict__ x, f16* __restrict__ xh,
                       const float* __restrict__ W1, f16* __restrict__ w1th,
                       const float* __restrict__ W2, f16* __restrict__ w2th,
                       const float* __restrict__ W_ih, const float* __restrict__ W_hh,
                       f16* __restrict__ wgh,
                       const int* __restrict__ batch, int* __restrict__ starts,
                       const int* __restrict__ ei, int* __restrict__ counts) {
  int b = blockIdx.x;
  if (b < 8192) {  // x -> f16, 4 elems/thread
    int i = (b * 256 + threadIdx.x) << 2;
    float4 v = *(const float4*)(x + i);
    f16x4 h = {(f16)v.x, (f16)v.y, (f16)v.z, (f16)v.w};
    *(f16x4*)(xh + i) = h;
  } else if (b < 8704) {  // W1 [256][512] -> w1th [512][256]
    int idx = (b - 8192) * 256 + threadIdx.x;
    int k = idx >> 9, n = idx & 511;
    w1th[(size_t)n * DIN + k] = (f16)W1[idx];
  } else if (b < 9728) {  // W2 [512][512] -> w2th [512][512]
    int idx = (b - 8704) * 256 + threadIdx.x;
    int k = idx >> 9, n = idx & 511;
    w2th[(size_t)n * DH + k] = (f16)W2[idx];
  } else if (b < 17920) {  // combined gates weight
    int idx = (b - 9728) * 256 + threadIdx.x;
    int n = idx >> 10, c = idx & 1023;
    float v = W_ih[(size_t)n * 1024 + c];
    if (c < 512) v += W_hh[(size_t)n * 512 + c];
    wgh[idx] = (f16)v;
  } else if (b == 17920) {  // batch starts via binary search
    int g = threadIdx.x;
    int lo = 0, hi = NN;
    while (lo < hi) {
      int mid = (lo + hi) >> 1;
      if (batch[mid] < g) lo = mid + 1; else hi = mid;
    }
    starts[g] = lo;
    if (g == 0) starts[NG] = NN;
  } else {  // edge degree count
    int e = (b - 17921) * 256 + threadIdx.x;
    if (e < NE) atomicAdd(&counts[ei[NE + e]], 1);
  }
}

// ---------------- fp16 MFMA GEMM (BK=64 single-buffer, m97 2-barrier structure) ----------------
// TERMS=1: C = A@B^T, pure fp16 (LDS 32K). TERMS=2: C = (Ahi+Alo)@B^T (LDS 48K).
// MODE 0: fp32 C partial at slice*M*N. MODE 1: +bias, relu, f16 out. MODE 2: f16 out.
template <int MODE, int TERMS>
__global__ __launch_bounds__(256) void k_mfma_gemm(
    const f16* __restrict__ Ahi, const f16* __restrict__ Alo,
    const f16* __restrict__ Bhi,
    float* __restrict__ C, f16* __restrict__ Cf16, const float* __restrict__ bias,
    int M, int N, int K, int lda, int ldb) {
  constexpr int BOFF = (TERMS == 2) ? 32768 : 16384;
  __shared__ char lds[(TERMS == 2) ? 49152 : 32768];

  int nbn = N >> 7;
  int nwg = (M >> 7) * nbn;
  int b = blockIdx.x;
  int slice = b / nwg;
  b -= slice * nwg;
  int koff = slice * K;
  int swz = (b & 7) * (nwg >> 3) + (b >> 3);  // nwg % 8 == 0 for all our shapes
  int bn = (swz % nbn) << 7;
  int bm = (swz / nbn) << 7;

  int tid = threadIdx.x;
  int w = tid >> 6, lane = tid & 63;
  int wm = (w >> 1) << 6, wn = (w & 1) << 6;
  int fr = lane & 15;
  int fq = lane >> 4;

  f32x4 acc[4][4];
#pragma unroll
  for (int i = 0; i < 4; ++i)
#pragma unroll
    for (int j = 0; j < 4; ++j) acc[i][j] = (f32x4){0.f, 0.f, 0.f, 0.f};

  for (int ks = 0; ks < K; ks += 64) {
#pragma unroll
    for (int i = 0; i < 4; ++i) {
      int L = i * 256 + tid;
      int row = L >> 3;
      int ke = ((L & 7) ^ (row & 7)) << 3;  // pre-swizzled global source
      int ldsoff = i * 4096 + w * 1024;     // wave-uniform base (+lane*16 by HW)
      gload16(Ahi + (size_t)(bm + row) * lda + koff + ks + ke, lds + ldsoff);
      if (TERMS == 2)
        gload16(Alo + (size_t)(bm + row) * lda + koff + ks + ke, lds + 16384 + ldsoff);
      gload16(Bhi + (size_t)(bn + row) * ldb + koff + ks + ke, lds + BOFF + ldsoff);
    }
    __syncthreads();
#pragma unroll
    for (int kk = 0; kk < 2; ++kk) {
      f16x8 ah[4], al[4], bh[4];
#pragma unroll
      for (int m = 0; m < 4; ++m) {
        int row = wm + m * 16 + fr;
        int boff = row * 128 + (((kk << 6) + (fq << 4)) ^ ((row & 7) << 4));
        ah[m] = *(const f16x8*)(lds + boff);
        if (TERMS == 2) al[m] = *(const f16x8*)(lds + 16384 + boff);
      }
#pragma unroll
      for (int n = 0; n < 4; ++n) {
        int row = wn + n * 16 + fr;
        int boff = row * 128 + (((kk << 6) + (fq << 4)) ^ ((row & 7) << 4));
        bh[n] = *(const f16x8*)(lds + BOFF + boff);
      }
#pragma unroll
      for (int m = 0; m < 4; ++m)
#pragma unroll
        for (int n = 0; n < 4; ++n) {
          acc[m][n] = __builtin_amdgcn_mfma_f32_16x16x32_f16(ah[m], bh[n], acc[m][n], 0, 0, 0);
          if (TERMS == 2)
            acc[m][n] = __builtin_amdgcn_mfma_f32_16x16x32_f16(al[m], bh[n], acc[m][n], 0, 0, 0);
        }
    }
    __syncthreads();
  }
#pragma unroll
  for (int m = 0; m < 4; ++m)
#pragma unroll
    for (int n = 0; n < 4; ++n)
#pragma unroll
      for (int i = 0; i < 4; ++i) {
        int r = bm + wm + m * 16 + fq * 4 + i;
        int c = bn + wn + n * 16 + fr;
        float val = acc[m][n][i];
        if (MODE == 1) {
          val += bias[c];
          val = fmaxf(val, 0.f);
          Cf16[(size_t)r * N + c] = (f16)val;
        } else if (MODE == 2) {
          Cf16[(size_t)r * N + c] = (f16)val;
        } else {
          C[(size_t)slice * M * N + (size_t)r * N + c] = val;
        }
      }
}

// ---------------- aggregation, 256-dim fp16 -> fp16. One wave per node, ILP-8. ----------------
__global__ __launch_bounds__(256) void k_agg256(const f16* __restrict__ xh,
                                                const int* __restrict__ offs,
                                                const int* __restrict__ csr,
                                                const float* __restrict__ dinv,
                                                f16* __restrict__ oh) {
  int wv = threadIdx.x >> 6, lane = threadIdx.x & 63;
  int v = blockIdx.x * 4 + wv;
  int f = lane << 2;
  int s = offs[v], t = offs[v + 1];
  float dv = dinv[v];
  f16x4 rs = *(const f16x4*)(xh + (size_t)v * DIN + f);  // self row, issued early
  float a0[4] = {}, a1[4] = {}, a2[4] = {}, a3[4] = {};
  for (int base = s; base < t; base += 64) {
    int rem = min(64, t - base);
    int idx = (lane < rem) ? csr[base + lane] : 0;
    float wl = (lane < rem) ? dinv[idx] : 0.f;
    int i = 0;
    for (; i + 7 < rem; i += 8) {
      int u[8]; float ww[8]; f16x4 r[8];
#pragma unroll
      for (int q = 0; q < 8; ++q) { u[q] = __shfl(idx, i + q); ww[q] = __shfl(wl, i + q); }
#pragma unroll
      for (int q = 0; q < 8; ++q) r[q] = *(const f16x4*)(xh + (size_t)u[q] * DIN + f);
#pragma unroll
      for (int k = 0; k < 4; ++k) {
        a0[k] += ww[0] * (float)r[0][k]; a1[k] += ww[1] * (float)r[1][k];
        a2[k] += ww[2] * (float)r[2][k]; a3[k] += ww[3] * (float)r[3][k];
        a0[k] += ww[4] * (float)r[4][k]; a1[k] += ww[5] * (float)r[5][k];
        a2[k] += ww[6] * (float)r[6][k]; a3[k] += ww[7] * (float)r[7][k];
      }
    }
    for (; i + 1 < rem; i += 2) {
      int u0 = __shfl(idx, i), u1 = __shfl(idx, i + 1);
      float w0 = __shfl(wl, i), w1 = __shfl(wl, i + 1);
      f16x4 r0 = *(const f16x4*)(xh + (size_t)u0 * DIN + f);
      f16x4 r1 = *(const f16x4*)(xh + (size_t)u1 * DIN + f);
#pragma unroll
      for (int k = 0; k < 4; ++k) { a0[k] += w0 * (float)r0[k]; a1[k] += w1 * (float)r1[k]; }
    }
    if (i < rem) {
      int u0 = __shfl(idx, i);
      float w0 = __shfl(wl, i);
      f16x4 r0 = *(const f16x4*)(xh + (size_t)u0 * DIN + f);
#pragma unroll
      for (int k = 0; k < 4; ++k) a0[k] += w0 * (float)r0[k];
    }
  }
  f16x4 vh;
#pragma unroll
  for (int k = 0; k < 4; ++k)
    vh[k] = (f16)((a0[k] + a1[k] + a2[k] + a3[k] + dv * (float)rs[k]) * dv);
  *(f16x4*)(oh + (size_t)v * DIN + f) = vh;
}

// ---------------- aggregation, 512-dim, both column halves in ONE launch ----------------
// Blocks [0, NN/4) do cols [0,256); blocks [NN/4, NN/2) do cols [256,512).
// In-order dispatch keeps concurrent random working set ~16 MB for better per-XCD L2 hit.
__global__ __launch_bounds__(256) void k_agg512(const f16* __restrict__ T2,
                                                const int* __restrict__ offs,
                                                const int* __restrict__ csr,
                                                const float* __restrict__ dinv,
                                                const float* __restrict__ bias,
                                                f16* __restrict__ H2) {
  int half = blockIdx.x / (NN / 4);
  int blk = blockIdx.x - half * (NN / 4);
  int wv = threadIdx.x >> 6, lane = threadIdx.x & 63;
  int v = blk * 4 + wv;
  int f = half * 256 + (lane << 2);
  int s = offs[v], t = offs[v + 1];
  float dv = dinv[v];
  f16x4 rs = *(const f16x4*)(T2 + (size_t)v * DH + f);  // self row, issued early
  float a0[4] = {}, a1[4] = {}, a2[4] = {}, a3[4] = {};
  for (int base = s; base < t; base += 64) {
    int rem = min(64, t - base);
    int idx = (lane < rem) ? csr[base + lane] : 0;
    float wl = (lane < rem) ? dinv[idx] : 0.f;
    int i = 0;
    for (; i + 7 < rem; i += 8) {
      int u[8]; float ww[8]; f16x4 r[8];
#pragma unroll
      for (int q = 0; q < 8; ++q) { u[q] = __shfl(idx, i + q); ww[q] = __shfl(wl, i + q); }
#pragma unroll
      for (int q = 0; q < 8; ++q) r[q] = *(const f16x4*)(T2 + (size_t)u[q] * DH + f);
#pragma unroll
      for (int k = 0; k < 4; ++k) {
        a0[k] += ww[0] * (float)r[0][k]; a1[k] += ww[1] * (float)r[1][k];
        a2[k] += ww[2] * (float)r[2][k]; a3[k] += ww[3] * (float)r[3][k];
        a0[k] += ww[4] * (float)r[4][k]; a1[k] += ww[5] * (float)r[5][k];
        a2[k] += ww[6] * (float)r[6][k]; a3[k] += ww[7] * (float)r[7][k];
      }
    }
    for (; i + 1 < rem; i += 2) {
      int u0 = __shfl(idx, i), u1 = __shfl(idx, i + 1);
      float w0 = __shfl(wl, i), w1 = __shfl(wl, i + 1);
      f16x4 r0 = *(const f16x4*)(T2 + (size_t)u0 * DH + f);
      f16x4 r1 = *(const f16x4*)(T2 + (size_t)u1 * DH + f);
#pragma unroll
      for (int k = 0; k < 4; ++k) { a0[k] += w0 * (float)r0[k]; a1[k] += w1 * (float)r1[k]; }
    }
    if (i < rem) {
      int u0 = __shfl(idx, i);
      float w0 = __shfl(wl, i);
      f16x4 r0 = *(const f16x4*)(T2 + (size_t)u0 * DH + f);
#pragma unroll
      for (int k = 0; k < 4; ++k) a0[k] += w0 * (float)r0[k];
    }
  }
  float4 bb = *(const float4*)(bias + f);
  float bbv[4] = {bb.x, bb.y, bb.z, bb.w};
  f16x4 out;
#pragma unroll
  for (int k = 0; k < 4; ++k)
    out[k] = (f16)((a0[k] + a1[k] + a2[k] + a3[k] + dv * (float)rs[k]) * dv + bbv[k]);
  *(f16x4*)(H2 + (size_t)v * DH + f) = out;
}

// ---------------- fused set2set step: LSTM + flash pool. 512 thr / 8 waves. ----------------
// STEP0=1: gates = b_ih + b_hh exactly (q_star=0, hs=0, cs=0) -> no GEMM, no cs read.
template <int STEP0>
__global__ __launch_bounds__(512) void k_step(const float* __restrict__ gp,
                                              const float* __restrict__ b_ih,
                                              const float* __restrict__ b_hh,
                                              float* __restrict__ cs,
                                              const f16* __restrict__ H2,
                                              const int* __restrict__ starts,
                                              float* __restrict__ qstar,
                                              f16* __restrict__ qhhi, f16* __restrict__ qhlo) {
  int g = blockIdx.x;
  int tid = threadIdx.x, wv = tid >> 6, lane = tid & 63;
  __shared__ float shs[512];
  __shared__ float lm[8], lsum[8];
  __shared__ float lr[8][512];

  // --- LSTM phase ---
  {
    int j = tid;
    float iv = b_ih[j]        + b_hh[j];
    float fv = b_ih[512 + j]  + b_hh[512 + j];
    float gv = b_ih[1024 + j] + b_hh[1024 + j];
    float ov = b_ih[1536 + j] + b_hh[1536 + j];
    if (!STEP0) {
      const float* g0 = gp + (size_t)g * 2048;
#pragma unroll
      for (int sl = 0; sl < 8; ++sl) {
        const float* gs = g0 + (size_t)sl * 524288;
        iv += gs[j]; fv += gs[512 + j]; gv += gs[1024 + j]; ov += gs[1536 + j];
      }
    }
    float si = 1.f / (1.f + expf(-iv));
    float sf = 1.f / (1.f + expf(-fv));
    float so = 1.f / (1.f + expf(-ov));
    float cprev = STEP0 ? 0.f : cs[(size_t)g * 512 + j];
    float c = sf * cprev + si * tanhf(gv);
    float h = so * tanhf(c);
    cs[(size_t)g * 512 + j] = c;
    shs[j] = h;
    qstar[(size_t)g * 1024 + j] = h;
    f16 hh, hl;
    split2h(h, hh, hl);
    qhhi[(size_t)g * 1024 + j] = hh;
    qhlo[(size_t)g * 1024 + j] = hl;
  }
  __syncthreads();

  // --- pool phase: 8 waves stride the graph's nodes, one-ahead row prefetch ---
  int s = starts[g], t = starts[g + 1];
  int cnt = t - s;
  float hsr[8];
#pragma unroll
  for (int k = 0; k < 8; ++k) hsr[k] = shs[lane * 8 + k];

  float m = -INFINITY, ssum = 0.f;
  float racc[8] = {};
  f16x8 rv = {};
  if (wv < cnt) rv = *(const f16x8*)(H2 + (size_t)(s + wv) * DH + lane * 8);
  for (int i = wv; i < cnt; i += 8) {
    f16x8 cur = rv;
    if (i + 8 < cnt) rv = *(const f16x8*)(H2 + (size_t)(s + i + 8) * DH + lane * 8);
    float e = 0.f;
#pragma unroll
    for (int k = 0; k < 8; ++k) e += (float)cur[k] * hsr[k];
#pragma unroll
    for (int o = 1; o < 64; o <<= 1) e += __shfl_xor(e, o);
    float mn = fmaxf(m, e);
    float scale = expf(m - mn);   // first iter: exp(-inf)=0
    float p = expf(e - mn);
    ssum = ssum * scale + p;
#pragma unroll
    for (int k = 0; k < 8; ++k) racc[k] = racc[k] * scale + p * (float)cur[k];
    m = mn;
  }
  if (lane == 0) { lm[wv] = m; lsum[wv] = ssum; }
#pragma unroll
  for (int k = 0; k < 8; ++k) lr[wv][lane * 8 + k] = racc[k];
  __syncthreads();
  float M = -INFINITY;
#pragma unroll
  for (int w2 = 0; w2 < 8; ++w2) M = fmaxf(M, lm[w2]);
  if (!(M > -3.0e38f)) M = 0.f;  // empty graph
  float denom = 0.f;
  float sc[8];
#pragma unroll
  for (int w2 = 0; w2 < 8; ++w2) { sc[w2] = expf(lm[w2] - M); denom += lsum[w2] * sc[w2]; }
  float inv = 1.f / fmaxf(denom, 1e-12f);
  int f = tid;  // 0..511
  float r = 0.f;
#pragma unroll
  for (int w2 = 0; w2 < 8; ++w2) r += lr[w2][f] * sc[w2];
  r *= inv;
  qstar[(size_t)g * 1024 + 512 + f] = r;
  f16 h0, l0;
  split2h(r, h0, l0);
  qhhi[(size_t)g * 1024 + 512 + f] = h0;
  qhlo[(size_t)g * 1024 + 512 + f] = l0;
}

// ---------------- launch ----------------
extern "C" void kernel_launch(void* const* d_in, const int* in_sizes, int n_in,
                              void* d_out, int out_size, void* d_ws, size_t ws_size,
                              hipStream_t stream) {
  const float* x     = (const float*)d_in[0];
  const int*   ei    = (const int*)d_in[1];
  const int*   batch = (const int*)d_in[2];
  const float* W1    = (const float*)d_in[3];
  const float* b1    = (const float*)d_in[4];
  const float* W2    = (const float*)d_in[5];
  const float* b2    = (const float*)d_in[6];
  const float* W_ih  = (const float*)d_in[7];
  const float* W_hh  = (const float*)d_in[8];
  const float* b_ih  = (const float*)d_in[9];
  const float* b_hh  = (const float*)d_in[10];
  float* qstar = (float*)d_out;

  char* w = (char*)d_ws;
  size_t off = 0;
  auto carve = [&](size_t bytes) -> void* {
    void* p = w + off;
    off += (bytes + 255) & ~(size_t)255;
    return p;
  };
  f16* xh      = (f16*)carve((size_t)NN * DIN * 2);
  f16* axh     = (f16*)carve((size_t)NN * DIN * 2);
  f16* h1h     = (f16*)carve((size_t)NN * DH * 2);
  f16* t2h     = (f16*)carve((size_t)NN * DH * 2);
  f16* H2h     = (f16*)carve((size_t)NN * DH * 2);
  f16* w1th    = (f16*)carve((size_t)DH * DIN * 2);
  f16* w2th    = (f16*)carve((size_t)DH * DH * 2);
  f16* wgh     = (f16*)carve((size_t)2048 * 1024 * 2);
  float* gp    = (float*)carve((size_t)8 * NG * 2048 * 4);
  // zero-group: counts + cursor (contiguous)
  int* counts  = (int*)carve((size_t)NN * 4);
  int* cursor  = (int*)carve((size_t)NN * 4);
  float* cs    = (float*)carve((size_t)NG * DOUT * 4);   // written by step0 before read
  f16* qhhi    = (f16*)carve((size_t)NG * 1024 * 2);     // written by step0 before read
  f16* qhlo    = (f16*)carve((size_t)NG * 1024 * 2);
  int* offs    = (int*)carve((size_t)(NN + 1) * 4);
  int* csr     = (int*)carve((size_t)NE * 4);
  float* dinv  = (float*)carve((size_t)NN * 4);
  int* starts  = (int*)carve((size_t)(NG + 1) * 4);
  int* bsum    = (int*)carve((size_t)256 * 4);
  int* boff    = (int*)carve((size_t)256 * 4);

  hipMemsetAsync(counts, 0, (size_t)2 * NN * 4, stream);

  k_prep<<<18945, 256, 0, stream>>>(x, xh, W1, w1th, W2, w2th, W_ih, W_hh, wgh,
                                    batch, starts, ei, counts);
  k_scanA<<<NN / 128, 128, 0, stream>>>(counts, bsum);
  k_scanB<<<1, 256, 0, stream>>>(bsum, boff, offs);
  k_scanC<<<NN / 128, 128, 0, stream>>>(counts, boff, offs, dinv);
  k_fill<<<NE / 256, 256, 0, stream>>>(ei, offs, cursor, csr);

  // layer 1: aggx = Agg(x) ; H1 = relu(aggx@W1 + b1)   [pure fp16 GEMM]
  k_agg256<<<NN / 4, 256, 0, stream>>>(xh, offs, csr, dinv, axh);
  k_mfma_gemm<1, 1><<<(NN / 128) * (DH / 128), 256, 0, stream>>>(
      axh, nullptr, w1th, nullptr, h1h, b1, NN, DH, DIN, DIN, DIN);
  // layer 2: t2 = H1@W2 ; H2 = Agg(t2) + b2            [pure fp16 GEMM, column-split agg]
  k_mfma_gemm<2, 1><<<(NN / 128) * (DH / 128), 256, 0, stream>>>(
      h1h, nullptr, w2th, nullptr, t2h, nullptr, NN, DH, DH, DH, DH);
  k_agg512<<<NN / 2, 256, 0, stream>>>(t2h, offs, csr, dinv, b2, H2h);

  // set2set: step 0 needs no GEMM (gates = b_ih + b_hh exactly)
  k_step<1><<<NG, 512, 0, stream>>>(nullptr, b_ih, b_hh, cs, H2h, starts, qstar, qhhi, qhlo);
  for (int step = 1; step < 3; ++step) {
    k_mfma_gemm<0, 2><<<8 * (NG / 128) * (2048 / 128), 256, 0, stream>>>(
        qhhi, qhlo, wgh, gp, nullptr, nullptr, NG, 2048, 128, 1024, 1024);
    k_step<0><<<NG, 512, 0, stream>>>(gp, b_ih, b_hh, cs, H2h, starts, qstar, qhhi, qhlo);
  }
}